// Round 1
// baseline (3725.509 us; speedup 1.0000x reference)
//
#include <hip/hip_runtime.h>
#include <cstdint>

#define N_NODES 100000
#define N_EDGES 500000
#define N_GRAPHS 128
#define HID 128

// ---- monotone float<->uint encoding for atomicMax-based segment_max ----
// enc(f) >= 0x007FFFFF for any finite/inf f, so enc==0 marks "no edge wrote here"
__device__ __forceinline__ unsigned encf(float f) {
    unsigned u = __float_as_uint(f);
    return (u & 0x80000000u) ? ~u : (u | 0x80000000u);
}
__device__ __forceinline__ float decf(unsigned e) {
    unsigned u = (e & 0x80000000u) ? (e & 0x7FFFFFFFu) : ~e;
    return __uint_as_float(u);
}

// ---- prep: fold key-embedding through W0; D = Wa[128:256]-Wa[0:128] ----
__global__ void prep_kernel(const float* __restrict__ W_enc, const float* __restrict__ b_enc,
                            const float* __restrict__ W0, const float* __restrict__ b0,
                            const float* __restrict__ W1a, const float* __restrict__ W2a,
                            float* __restrict__ wkey, float* __restrict__ bias0,
                            float* __restrict__ D1, float* __restrict__ D2) {
    int tid = threadIdx.x;
    if (tid < HID) {
        float wk = 0.f, bk = b0[tid];
        for (int k = 0; k < 32; ++k) {
            float w = W0[(15 + k) * HID + tid];
            wk += W_enc[k] * w;
            bk += b_enc[k] * w;
        }
        wkey[tid] = wk;
        bias0[tid] = bk;
    }
    for (int i = tid; i < HID * HID; i += blockDim.x) {
        D1[i] = W1a[HID * HID + i] - W1a[i];
        D2[i] = W2a[HID * HID + i] - W2a[i];
    }
}

// ---- encoder: h = relu(features @ W0[0:15] + key*wkey + bias0) ----
__global__ __launch_bounds__(256) void encode_kernel(const float* __restrict__ x,
                                                     const float* __restrict__ W0,
                                                     const float* __restrict__ wkey,
                                                     const float* __restrict__ bias0,
                                                     float* __restrict__ h) {
    int n = blockIdx.x * 2 + (threadIdx.x >> 7);
    int j = threadIdx.x & 127;
    const float* xr = x + n * 16;
    float acc = bias0[j] + xr[0] * wkey[j];
#pragma unroll
    for (int f = 0; f < 15; ++f)
        acc = fmaf(xr[1 + f], W0[f * HID + j], acc);
    h[n * HID + j] = fmaxf(acc, 0.f);
}

// ---- generic (N x 128) @ (128 x 128) + bias ----
__global__ __launch_bounds__(256) void mm128_kernel(const float* __restrict__ in,
                                                    const float* __restrict__ W,
                                                    const float* __restrict__ bias,
                                                    float* __restrict__ out, int nrows) {
    __shared__ float4 sW[128 * 32];                 // 64 KB, chunk-swizzled
    __shared__ __align__(16) float sA[64 * 132];    // 33.8 KB
    int tid = threadIdx.x;
    for (int idx = tid; idx < 128 * 32; idx += 256) {
        int k = idx >> 5, c = idx & 31;
        int p = ((c & 1) << 4) | (c >> 1);
        sW[k * 32 + p] = ((const float4*)W)[idx];
    }
    int n0 = blockIdx.x * 64;
#pragma unroll
    for (int q = 0; q < 8; ++q) {
        int idx = q * 256 + tid;
        int r = idx >> 5, c4 = idx & 31;
        int n = n0 + r;
        float4 vv = (n < nrows) ? ((const float4*)(in + (size_t)n * HID))[c4]
                                : make_float4(0.f, 0.f, 0.f, 0.f);
        *((float4*)(sA + r * 132 + c4 * 4)) = vv;
    }
    __syncthreads();
    int cg = tid & 15;   // cols j = cg*8 .. cg*8+7
    int rg = tid >> 4;   // rows rg*4 .. rg*4+3
    float acc[4][8];
#pragma unroll
    for (int r = 0; r < 4; ++r)
#pragma unroll
        for (int q = 0; q < 8; ++q) acc[r][q] = 0.f;
#pragma unroll 4
    for (int k = 0; k < 128; ++k) {
        float4 w0 = sW[k * 32 + cg];
        float4 w1 = sW[k * 32 + 16 + cg];
#pragma unroll
        for (int r = 0; r < 4; ++r) {
            float a = sA[(rg * 4 + r) * 132 + k];
            acc[r][0] = fmaf(a, w0.x, acc[r][0]);
            acc[r][1] = fmaf(a, w0.y, acc[r][1]);
            acc[r][2] = fmaf(a, w0.z, acc[r][2]);
            acc[r][3] = fmaf(a, w0.w, acc[r][3]);
            acc[r][4] = fmaf(a, w1.x, acc[r][4]);
            acc[r][5] = fmaf(a, w1.y, acc[r][5]);
            acc[r][6] = fmaf(a, w1.z, acc[r][6]);
            acc[r][7] = fmaf(a, w1.w, acc[r][7]);
        }
    }
    float b0v = bias ? bias[cg * 8 + 0] : 0.f;
    float b1v = bias ? bias[cg * 8 + 1] : 0.f;
    float b2v = bias ? bias[cg * 8 + 2] : 0.f;
    float b3v = bias ? bias[cg * 8 + 3] : 0.f;
    float b4v = bias ? bias[cg * 8 + 4] : 0.f;
    float b5v = bias ? bias[cg * 8 + 5] : 0.f;
    float b6v = bias ? bias[cg * 8 + 6] : 0.f;
    float b7v = bias ? bias[cg * 8 + 7] : 0.f;
#pragma unroll
    for (int r = 0; r < 4; ++r) {
        int n = n0 + rg * 4 + r;
        if (n < nrows) {
            float4 o0 = make_float4(acc[r][0] + b0v, acc[r][1] + b1v, acc[r][2] + b2v, acc[r][3] + b3v);
            float4 o1 = make_float4(acc[r][4] + b4v, acc[r][5] + b5v, acc[r][6] + b6v, acc[r][7] + b7v);
            float4* op = (float4*)(out + (size_t)n * HID + cg * 8);
            op[0] = o0;
            op[1] = o1;
        }
    }
}

// ---- edge conv: pre = u[src]+v[dst]+(k_s-k_d)*w256 ; t=leaky(pre) ; msg=t@Wb ; atomicMax into agg[dst] ----
__global__ __launch_bounds__(256) void edge_kernel(const float* __restrict__ u,
                                                   const float* __restrict__ v,
                                                   const float* __restrict__ x,
                                                   const int* __restrict__ src,
                                                   const int* __restrict__ dst,
                                                   const float* __restrict__ Wb,
                                                   const float* __restrict__ wlast,
                                                   unsigned* __restrict__ agg) {
    __shared__ float4 sW[128 * 32];                 // 64 KB, chunk-swizzled
    __shared__ __align__(16) float sT[32 * 132];    // 16.9 KB
    __shared__ __align__(16) float sW256[128];
    __shared__ int sSrc[32], sDst[32];
    __shared__ float sKd[32];
    int tid = threadIdx.x;
    for (int idx = tid; idx < 128 * 32; idx += 256) {
        int k = idx >> 5, c = idx & 31;
        int p = ((c & 1) << 4) | (c >> 1);
        sW[k * 32 + p] = ((const float4*)Wb)[idx];
    }
    if (tid < 128) sW256[tid] = wlast[tid];

    const int nChunks = N_EDGES / 32;
    for (int ch = blockIdx.x; ch < nChunks; ch += gridDim.x) {
        __syncthreads();
        if (tid < 32) {
            int e = ch * 32 + tid;
            int s = src[e], d = dst[e];
            sSrc[tid] = s;
            sDst[tid] = d;
            sKd[tid] = x[(size_t)s * 16] - x[(size_t)d * 16];
        }
        __syncthreads();
        {
            int e = tid >> 3;
            int kb = (tid & 7) << 4;
            int s = sSrc[e], d = sDst[e];
            float kd = sKd[e];
            const float4* ur = (const float4*)(u + (size_t)s * HID + kb);
            const float4* vr = (const float4*)(v + (size_t)d * HID + kb);
            const float4* wr = (const float4*)(sW256 + kb);
            float* trow = sT + e * 132 + kb;
#pragma unroll
            for (int q = 0; q < 4; ++q) {
                float4 uu = ur[q], vv = vr[q], ww = wr[q];
                float4 p4;
                p4.x = fmaf(kd, ww.x, uu.x + vv.x);
                p4.y = fmaf(kd, ww.y, uu.y + vv.y);
                p4.z = fmaf(kd, ww.z, uu.z + vv.z);
                p4.w = fmaf(kd, ww.w, uu.w + vv.w);
                p4.x = p4.x > 0.f ? p4.x : 0.1f * p4.x;
                p4.y = p4.y > 0.f ? p4.y : 0.1f * p4.y;
                p4.z = p4.z > 0.f ? p4.z : 0.1f * p4.z;
                p4.w = p4.w > 0.f ? p4.w : 0.1f * p4.w;
                *((float4*)(trow + q * 4)) = p4;
            }
        }
        __syncthreads();
        int cg = tid & 15;        // cols j = cg*8..+7
        int eg = tid >> 4;        // edges eg*2, eg*2+1
        int e0 = eg * 2, e1 = e0 + 1;
        float acc0[8] = {0.f, 0.f, 0.f, 0.f, 0.f, 0.f, 0.f, 0.f};
        float acc1[8] = {0.f, 0.f, 0.f, 0.f, 0.f, 0.f, 0.f, 0.f};
#pragma unroll 8
        for (int k = 0; k < 128; ++k) {
            float4 w0 = sW[k * 32 + cg];
            float4 w1 = sW[k * 32 + 16 + cg];
            float t0 = sT[e0 * 132 + k];
            float t1 = sT[e1 * 132 + k];
            acc0[0] = fmaf(t0, w0.x, acc0[0]);
            acc0[1] = fmaf(t0, w0.y, acc0[1]);
            acc0[2] = fmaf(t0, w0.z, acc0[2]);
            acc0[3] = fmaf(t0, w0.w, acc0[3]);
            acc0[4] = fmaf(t0, w1.x, acc0[4]);
            acc0[5] = fmaf(t0, w1.y, acc0[5]);
            acc0[6] = fmaf(t0, w1.z, acc0[6]);
            acc0[7] = fmaf(t0, w1.w, acc0[7]);
            acc1[0] = fmaf(t1, w0.x, acc1[0]);
            acc1[1] = fmaf(t1, w0.y, acc1[1]);
            acc1[2] = fmaf(t1, w0.z, acc1[2]);
            acc1[3] = fmaf(t1, w0.w, acc1[3]);
            acc1[4] = fmaf(t1, w1.x, acc1[4]);
            acc1[5] = fmaf(t1, w1.y, acc1[5]);
            acc1[6] = fmaf(t1, w1.z, acc1[6]);
            acc1[7] = fmaf(t1, w1.w, acc1[7]);
        }
        int d0 = sDst[e0], d1 = sDst[e1];
        unsigned* a0 = agg + (size_t)d0 * HID + cg * 8;
        unsigned* a1 = agg + (size_t)d1 * HID + cg * 8;
#pragma unroll
        for (int q = 0; q < 8; ++q) {
            atomicMax(a0 + q, encf(acc0[q]));
            atomicMax(a1 + q, encf(acc1[q]));
        }
    }
}

// ---- combine: out = relu((agg? dec(agg)+bb : 0) + base) ----
__global__ __launch_bounds__(256) void combine_kernel(const unsigned* __restrict__ agg,
                                                      const float* __restrict__ bb,
                                                      const float* __restrict__ base,
                                                      float* __restrict__ out) {
    size_t i = (size_t)blockIdx.x * 256 + threadIdx.x;
    unsigned e = agg[i];
    int j = (int)(i & 127);
    float val = (e == 0u) ? 0.f : (decf(e) + bb[j]);
    out[i] = fmaxf(val + base[i], 0.f);
}

// ---- pooling: batch is sorted, one block per graph, binary-search bounds ----
__global__ __launch_bounds__(256) void pool_kernel(const float* __restrict__ x1,
                                                   const float* __restrict__ x2,
                                                   const int* __restrict__ batch,
                                                   float* __restrict__ pooled) {
    int g = blockIdx.x;
    int tid = threadIdx.x;
    int lo = 0, hi = N_NODES;
    while (lo < hi) { int mid = (lo + hi) >> 1; if (batch[mid] < g) lo = mid + 1; else hi = mid; }
    int start = lo;
    hi = N_NODES;
    while (lo < hi) { int mid = (lo + hi) >> 1; if (batch[mid] < g + 1) lo = mid + 1; else hi = mid; }
    int end = lo;
    const float* srcp = (tid < 128) ? (x1 + tid) : (x2 + (tid - 128));
    float mx = -INFINITY, sm = 0.f;
    for (int n = start; n < end; ++n) {
        float vv = srcp[(size_t)n * HID];
        mx = fmaxf(mx, vv);
        sm += vv;
    }
    int cnt = end - start;
    pooled[(size_t)g * 512 + tid] = cnt ? mx : 0.f;
    pooled[(size_t)g * 512 + 256 + tid] = sm / (float)(cnt > 1 ? cnt : 1);
}

// ---- final MLP + log_softmax: one block per graph ----
__global__ __launch_bounds__(128) void final_kernel(const float* __restrict__ pooled,
                                                    const float* __restrict__ Wf1,
                                                    const float* __restrict__ bf1,
                                                    const float* __restrict__ Wf2,
                                                    const float* __restrict__ bf2,
                                                    float* __restrict__ out) {
    __shared__ float sP[512];
    __shared__ float sH[128];
    int g = blockIdx.x, tid = threadIdx.x;
#pragma unroll
    for (int q = 0; q < 4; ++q) sP[q * 128 + tid] = pooled[(size_t)g * 512 + q * 128 + tid];
    __syncthreads();
    float acc = bf1[tid];
    for (int k = 0; k < 512; ++k) acc = fmaf(sP[k], Wf1[k * HID + tid], acc);
    sH[tid] = fmaxf(acc, 0.f);
    __syncthreads();
    if (tid < 2) {
        float l = bf2[tid];
        for (int k = 0; k < 128; ++k) l = fmaf(sH[k], Wf2[k * 2 + tid], l);
        sP[tid] = l;
    }
    __syncthreads();
    if (tid == 0) {
        float l0 = sP[0], l1 = sP[1];
        float m = fmaxf(l0, l1);
        float ls = m + logf(expf(l0 - m) + expf(l1 - m));
        out[g * 2 + 0] = l0 - ls;
        out[g * 2 + 1] = l1 - ls;
    }
}

extern "C" void kernel_launch(void* const* d_in, const int* in_sizes, int n_in,
                              void* d_out, int out_size, void* d_ws, size_t ws_size,
                              hipStream_t stream) {
    const float* x     = (const float*)d_in[0];
    const float* W_enc = (const float*)d_in[1];
    const float* b_enc = (const float*)d_in[2];
    const float* W0    = (const float*)d_in[3];
    const float* b0    = (const float*)d_in[4];
    const float* W1a   = (const float*)d_in[5];
    const float* b1a   = (const float*)d_in[6];
    const float* W1b   = (const float*)d_in[7];
    const float* b1b   = (const float*)d_in[8];
    const float* W2a   = (const float*)d_in[9];
    const float* b2a   = (const float*)d_in[10];
    const float* W2b   = (const float*)d_in[11];
    const float* b2b   = (const float*)d_in[12];
    const float* Wf1   = (const float*)d_in[13];
    const float* bf1   = (const float*)d_in[14];
    const float* Wf2   = (const float*)d_in[15];
    const float* bf2   = (const float*)d_in[16];
    const int* src1    = (const int*)d_in[17];
    const int* dst1    = (const int*)d_in[18];
    const int* src2    = (const int*)d_in[19];
    const int* dst2    = (const int*)d_in[20];
    const int* batch   = (const int*)d_in[21];

    const size_t NB = (size_t)N_NODES * HID;   // 12.8M elements
    float* buf0 = (float*)d_ws;                // h -> x1 (in place)
    float* buf1 = buf0 + NB;                   // u  -> x2
    float* buf2 = buf1 + NB;                   // v
    unsigned* agg = (unsigned*)(buf2 + NB);    // encoded segment-max
    float* wkey  = (float*)(agg + NB);
    float* bias0 = wkey + 128;
    float* D1    = bias0 + 128;
    float* D2    = D1 + HID * HID;
    float* pooled = D2 + HID * HID;            // 128*512

    prep_kernel<<<1, 256, 0, stream>>>(W_enc, b_enc, W0, b0, W1a, W2a, wkey, bias0, D1, D2);
    encode_kernel<<<N_NODES / 2, 256, 0, stream>>>(x, W0, wkey, bias0, buf0);

    const int mmGrid = (N_NODES + 63) / 64;
    // layer 1
    mm128_kernel<<<mmGrid, 256, 0, stream>>>(buf0, W1a, nullptr, buf1, N_NODES);       // u1
    mm128_kernel<<<mmGrid, 256, 0, stream>>>(buf0, D1, b1a, buf2, N_NODES);            // v1 (+b1a)
    hipMemsetAsync(agg, 0, NB * sizeof(unsigned), stream);
    edge_kernel<<<1024, 256, 0, stream>>>(buf1, buf2, x, src1, dst1, W1b, W1a + 256 * HID, agg);
    combine_kernel<<<(int)(NB / 256), 256, 0, stream>>>(agg, b1b, buf0, buf0);         // x1 in place
    // layer 2
    mm128_kernel<<<mmGrid, 256, 0, stream>>>(buf0, W2a, nullptr, buf1, N_NODES);       // u2
    mm128_kernel<<<mmGrid, 256, 0, stream>>>(buf0, D2, b2a, buf2, N_NODES);            // v2 (+b2a)
    hipMemsetAsync(agg, 0, NB * sizeof(unsigned), stream);
    edge_kernel<<<1024, 256, 0, stream>>>(buf1, buf2, x, src2, dst2, W2b, W2a + 256 * HID, agg);
    combine_kernel<<<(int)(NB / 256), 256, 0, stream>>>(agg, b2b, buf0, buf1);         // x2 -> buf1

    pool_kernel<<<N_GRAPHS, 256, 0, stream>>>(buf0, buf1, batch, pooled);
    final_kernel<<<N_GRAPHS, 128, 0, stream>>>(pooled, Wf1, bf1, Wf2, bf2, (float*)d_out);
}

// Round 2
// 3406.401 us; speedup vs baseline: 1.0937x; 1.0937x over previous
//
#include <hip/hip_runtime.h>
#include <cstdint>

#define N_NODES 100000
#define N_EDGES 500000
#define N_GRAPHS 128
#define HID 128

// ---- monotone float<->uint encoding for atomicMax-based segment_max ----
// enc==0 marks "no edge wrote here" (unreachable for finite inputs)
__device__ __forceinline__ unsigned encf(float f) {
    unsigned u = __float_as_uint(f);
    return (u & 0x80000000u) ? ~u : (u | 0x80000000u);
}
__device__ __forceinline__ float decf(unsigned e) {
    unsigned u = (e & 0x80000000u) ? (e & 0x7FFFFFFFu) : ~e;
    return __uint_as_float(u);
}

// ---- prep: fold key-embedding through W0; D = Wa[128:256]-Wa[0:128] ----
__global__ void prep_kernel(const float* __restrict__ W_enc, const float* __restrict__ b_enc,
                            const float* __restrict__ W0, const float* __restrict__ b0,
                            const float* __restrict__ W1a, const float* __restrict__ W2a,
                            float* __restrict__ wkey, float* __restrict__ bias0,
                            float* __restrict__ D1, float* __restrict__ D2) {
    int tid = threadIdx.x;
    if (tid < HID) {
        float wk = 0.f, bk = b0[tid];
        for (int k = 0; k < 32; ++k) {
            float w = W0[(15 + k) * HID + tid];
            wk += W_enc[k] * w;
            bk += b_enc[k] * w;
        }
        wkey[tid] = wk;
        bias0[tid] = bk;
    }
    for (int i = tid; i < HID * HID; i += blockDim.x) {
        D1[i] = W1a[HID * HID + i] - W1a[i];
        D2[i] = W2a[HID * HID + i] - W2a[i];
    }
}

// ---- encoder: h = relu(features @ W0[0:15] + key*wkey + bias0) ----
__global__ __launch_bounds__(256) void encode_kernel(const float* __restrict__ x,
                                                     const float* __restrict__ W0,
                                                     const float* __restrict__ wkey,
                                                     const float* __restrict__ bias0,
                                                     float* __restrict__ h) {
    int n = blockIdx.x * 2 + (threadIdx.x >> 7);
    int j = threadIdx.x & 127;
    const float* xr = x + n * 16;
    float acc = bias0[j] + xr[0] * wkey[j];
#pragma unroll
    for (int f = 0; f < 15; ++f)
        acc = fmaf(xr[1 + f], W0[f * HID + j], acc);
    h[n * HID + j] = fmaxf(acc, 0.f);
}

// ---- dual (N x 128) @ (128 x 128): out_u = in@Wu ; out_v = in@Wv + bv ----
// Weights read straight from global (16-way broadcast-coalesced per wave, L1/L2
// resident) -> LDS is only the 33.8KB input tile -> 4 blocks/CU.
__global__ __launch_bounds__(256, 4) void mm128_dual_kernel(const float* __restrict__ in,
                                                            const float* __restrict__ Wu,
                                                            const float* __restrict__ Wv,
                                                            const float* __restrict__ bv,
                                                            float* __restrict__ outu,
                                                            float* __restrict__ outv, int nrows) {
    __shared__ __align__(16) float sA[64 * 132];
    int tid = threadIdx.x;
    int n0 = blockIdx.x * 64;
#pragma unroll
    for (int q = 0; q < 8; ++q) {
        int idx = q * 256 + tid;
        int r = idx >> 5, c4 = idx & 31;
        int n = n0 + r;
        float4 vv = (n < nrows) ? ((const float4*)(in + (size_t)n * HID))[c4]
                                : make_float4(0.f, 0.f, 0.f, 0.f);
        *((float4*)(sA + r * 132 + c4 * 4)) = vv;
    }
    __syncthreads();
    int cg = tid & 15;   // cols cg*8..+7
    int rg = tid >> 4;   // rows rg*4..+3
#pragma unroll
    for (int pass = 0; pass < 2; ++pass) {
        const float* W = pass ? Wv : Wu;
        float* out = pass ? outv : outu;
        const float* WC = W + cg * 8;
        float acc[4][8];
#pragma unroll
        for (int r = 0; r < 4; ++r)
#pragma unroll
            for (int q = 0; q < 8; ++q) acc[r][q] = 0.f;
#pragma unroll 2
        for (int k4 = 0; k4 < 128; k4 += 4) {
            float4 a[4];
#pragma unroll
            for (int r = 0; r < 4; ++r)
                a[r] = *(const float4*)(sA + (rg * 4 + r) * 132 + k4);
#pragma unroll
            for (int kk = 0; kk < 4; ++kk) {
                const float4* wr = (const float4*)(WC + (k4 + kk) * HID);
                float4 w0 = wr[0], w1 = wr[1];
#pragma unroll
                for (int r = 0; r < 4; ++r) {
                    float av = ((const float*)&a[r])[kk];
                    acc[r][0] = fmaf(av, w0.x, acc[r][0]);
                    acc[r][1] = fmaf(av, w0.y, acc[r][1]);
                    acc[r][2] = fmaf(av, w0.z, acc[r][2]);
                    acc[r][3] = fmaf(av, w0.w, acc[r][3]);
                    acc[r][4] = fmaf(av, w1.x, acc[r][4]);
                    acc[r][5] = fmaf(av, w1.y, acc[r][5]);
                    acc[r][6] = fmaf(av, w1.z, acc[r][6]);
                    acc[r][7] = fmaf(av, w1.w, acc[r][7]);
                }
            }
        }
        float bvv[8];
#pragma unroll
        for (int q = 0; q < 8; ++q) bvv[q] = pass ? bv[cg * 8 + q] : 0.f;
#pragma unroll
        for (int r = 0; r < 4; ++r) {
            int n = n0 + rg * 4 + r;
            if (n < nrows) {
                float4 o0 = make_float4(acc[r][0] + bvv[0], acc[r][1] + bvv[1],
                                        acc[r][2] + bvv[2], acc[r][3] + bvv[3]);
                float4 o1 = make_float4(acc[r][4] + bvv[4], acc[r][5] + bvv[5],
                                        acc[r][6] + bvv[6], acc[r][7] + bvv[7]);
                float4* op = (float4*)(out + (size_t)n * HID + cg * 8);
                op[0] = o0;
                op[1] = o1;
            }
        }
    }
}

// ---- edge conv v2: pipelined, 4 blocks/CU, weights from global ----
// pre = u[src]+v[dst]+(k_s-k_d)*w256 ; t=leaky(pre) ; msg=t@Wb ; atomicMax agg[dst]
__global__ __launch_bounds__(256, 4) void edge_kernel(const float* __restrict__ u,
                                                      const float* __restrict__ v,
                                                      const float* __restrict__ x,
                                                      const int* __restrict__ src,
                                                      const int* __restrict__ dst,
                                                      const float* __restrict__ Wb,
                                                      const float* __restrict__ wlast,
                                                      unsigned* __restrict__ agg) {
    __shared__ __align__(16) float sT[2][32 * 132];   // 33.8 KB double-buffered t
    __shared__ int sDst[2][32];
    int tid = threadIdx.x;
    int eloc = tid >> 3;        // edge slot 0..31
    int kb = (tid & 7) << 4;    // k-offset 0,16,...,112 (floats)

    // per-thread constant slice of w256 (key-diff row of Wa)
    float4 wk[4];
    {
        const float4* wr = (const float4*)(wlast + kb);
        wk[0] = wr[0]; wk[1] = wr[1]; wk[2] = wr[2]; wk[3] = wr[3];
    }

    const int nChunks = N_EDGES / 32;
    const int G = gridDim.x;
    int ch = blockIdx.x;

    // prologue: indices for chunk ch (dist-0) and ch+G (dist-1)
    int sCur = src[ch * 32 + eloc];
    int dCur = dst[ch * 32 + eloc];
    int chN = ch + G;
    int eSafe = (chN < nChunks) ? (chN * 32 + eloc) : eloc;
    int sN = src[eSafe];
    int dN = dst[eSafe];

    // prologue: issue gathers for chunk ch
    float4 uR[4], vR[4];
    float xs, xd;
    {
        const float4* ur = (const float4*)(u + (size_t)sCur * HID + kb);
        const float4* vr = (const float4*)(v + (size_t)dCur * HID + kb);
#pragma unroll
        for (int q = 0; q < 4; ++q) { uR[q] = ur[q]; vR[q] = vr[q]; }
        xs = x[(size_t)sCur * 16];
        xd = x[(size_t)dCur * 16];
    }

    int buf = 0;
    for (; ch < nChunks; ch += G) {
        // phase 1: t = leaky(u+v+kd*w256) -> sT[buf]
        float kd = xs - xd;
        float* trow = &sT[buf][eloc * 132 + kb];
#pragma unroll
        for (int q = 0; q < 4; ++q) {
            float4 uu = uR[q], vv = vR[q], ww = wk[q];
            float4 p4;
            p4.x = fmaf(kd, ww.x, uu.x + vv.x);
            p4.y = fmaf(kd, ww.y, uu.y + vv.y);
            p4.z = fmaf(kd, ww.z, uu.z + vv.z);
            p4.w = fmaf(kd, ww.w, uu.w + vv.w);
            p4.x = p4.x > 0.f ? p4.x : 0.1f * p4.x;
            p4.y = p4.y > 0.f ? p4.y : 0.1f * p4.y;
            p4.z = p4.z > 0.f ? p4.z : 0.1f * p4.z;
            p4.w = p4.w > 0.f ? p4.w : 0.1f * p4.w;
            *((float4*)(trow + 0)) = p4;   // placeholder overwritten below
            trow += 0;                      // (kept simple; real store below)
            ((float4*)(&sT[buf][eloc * 132 + kb]))[q] = p4;
        }
        if ((tid & 7) == 0) sDst[buf][eloc] = dCur;

        // phase 2: rotate prefetched indices, issue next gathers + dist-2 index loads
        int chNext = ch + G;
        if (chNext < nChunks) {
            sCur = sN; dCur = dN;
            const float4* ur = (const float4*)(u + (size_t)sCur * HID + kb);
            const float4* vr = (const float4*)(v + (size_t)dCur * HID + kb);
#pragma unroll
            for (int q = 0; q < 4; ++q) { uR[q] = ur[q]; vR[q] = vr[q]; }
            xs = x[(size_t)sCur * 16];
            xd = x[(size_t)dCur * 16];
            int chNN = chNext + G;
            int eS2 = (chNN < nChunks) ? (chNN * 32 + eloc) : eloc;
            sN = src[eS2];
            dN = dst[eS2];
        }
        __syncthreads();

        // phase 3: msg = t @ Wb (weights from global, broadcast-coalesced) + atomicMax
        int cg = tid & 15;        // cols cg*8..+7
        int eg = tid >> 4;        // edges eg*2, eg*2+1
        int e0 = eg * 2, e1 = e0 + 1;
        const float* t0p = &sT[buf][e0 * 132];
        const float* t1p = &sT[buf][e1 * 132];
        const float* WC = Wb + cg * 8;
        float acc0[8], acc1[8];
#pragma unroll
        for (int q = 0; q < 8; ++q) { acc0[q] = 0.f; acc1[q] = 0.f; }
#pragma unroll 2
        for (int k4 = 0; k4 < 128; k4 += 4) {
            float4 t0 = *(const float4*)(t0p + k4);
            float4 t1 = *(const float4*)(t1p + k4);
#pragma unroll
            for (int kk = 0; kk < 4; ++kk) {
                const float4* wr = (const float4*)(WC + (k4 + kk) * HID);
                float4 w0 = wr[0], w1 = wr[1];
                float a0 = ((const float*)&t0)[kk];
                float a1 = ((const float*)&t1)[kk];
                acc0[0] = fmaf(a0, w0.x, acc0[0]);
                acc0[1] = fmaf(a0, w0.y, acc0[1]);
                acc0[2] = fmaf(a0, w0.z, acc0[2]);
                acc0[3] = fmaf(a0, w0.w, acc0[3]);
                acc0[4] = fmaf(a0, w1.x, acc0[4]);
                acc0[5] = fmaf(a0, w1.y, acc0[5]);
                acc0[6] = fmaf(a0, w1.z, acc0[6]);
                acc0[7] = fmaf(a0, w1.w, acc0[7]);
                acc1[0] = fmaf(a1, w0.x, acc1[0]);
                acc1[1] = fmaf(a1, w0.y, acc1[1]);
                acc1[2] = fmaf(a1, w0.z, acc1[2]);
                acc1[3] = fmaf(a1, w0.w, acc1[3]);
                acc1[4] = fmaf(a1, w1.x, acc1[4]);
                acc1[5] = fmaf(a1, w1.y, acc1[5]);
                acc1[6] = fmaf(a1, w1.z, acc1[6]);
                acc1[7] = fmaf(a1, w1.w, acc1[7]);
            }
        }
        int d0 = sDst[buf][e0], d1 = sDst[buf][e1];
        unsigned* a0p = agg + (size_t)d0 * HID + cg * 8;
        unsigned* a1p = agg + (size_t)d1 * HID + cg * 8;
#pragma unroll
        for (int q = 0; q < 8; ++q) {
            atomicMax(a0p + q, encf(acc0[q]));
            atomicMax(a1p + q, encf(acc1[q]));
        }
        buf ^= 1;
    }
}

// ---- combine: out = relu((agg? dec(agg)+bb : 0) + base) ----
__global__ __launch_bounds__(256) void combine_kernel(const unsigned* __restrict__ agg,
                                                      const float* __restrict__ bb,
                                                      const float* __restrict__ base,
                                                      float* __restrict__ out) {
    size_t i = (size_t)blockIdx.x * 256 + threadIdx.x;
    unsigned e = agg[i];
    int j = (int)(i & 127);
    float val = (e == 0u) ? 0.f : (decf(e) + bb[j]);
    out[i] = fmaxf(val + base[i], 0.f);
}

// ---- pooling: batch is sorted, one block per graph, binary-search bounds ----
__global__ __launch_bounds__(256) void pool_kernel(const float* __restrict__ x1,
                                                   const float* __restrict__ x2,
                                                   const int* __restrict__ batch,
                                                   float* __restrict__ pooled) {
    int g = blockIdx.x;
    int tid = threadIdx.x;
    int lo = 0, hi = N_NODES;
    while (lo < hi) { int mid = (lo + hi) >> 1; if (batch[mid] < g) lo = mid + 1; else hi = mid; }
    int start = lo;
    hi = N_NODES;
    while (lo < hi) { int mid = (lo + hi) >> 1; if (batch[mid] < g + 1) lo = mid + 1; else hi = mid; }
    int end = lo;
    const float* srcp = (tid < 128) ? (x1 + tid) : (x2 + (tid - 128));
    float mx = -INFINITY, sm = 0.f;
#pragma unroll 4
    for (int n = start; n < end; ++n) {
        float vv = srcp[(size_t)n * HID];
        mx = fmaxf(mx, vv);
        sm += vv;
    }
    int cnt = end - start;
    pooled[(size_t)g * 512 + tid] = cnt ? mx : 0.f;
    pooled[(size_t)g * 512 + 256 + tid] = sm / (float)(cnt > 1 ? cnt : 1);
}

// ---- final MLP + log_softmax: one block per graph ----
__global__ __launch_bounds__(128) void final_kernel(const float* __restrict__ pooled,
                                                    const float* __restrict__ Wf1,
                                                    const float* __restrict__ bf1,
                                                    const float* __restrict__ Wf2,
                                                    const float* __restrict__ bf2,
                                                    float* __restrict__ out) {
    __shared__ float sP[512];
    __shared__ float sH[128];
    int g = blockIdx.x, tid = threadIdx.x;
#pragma unroll
    for (int q = 0; q < 4; ++q) sP[q * 128 + tid] = pooled[(size_t)g * 512 + q * 128 + tid];
    __syncthreads();
    float acc = bf1[tid];
    for (int k = 0; k < 512; ++k) acc = fmaf(sP[k], Wf1[k * HID + tid], acc);
    sH[tid] = fmaxf(acc, 0.f);
    __syncthreads();
    if (tid < 2) {
        float l = bf2[tid];
        for (int k = 0; k < 128; ++k) l = fmaf(sH[k], Wf2[k * 2 + tid], l);
        sP[tid] = l;
    }
    __syncthreads();
    if (tid == 0) {
        float l0 = sP[0], l1 = sP[1];
        float m = fmaxf(l0, l1);
        float ls = m + logf(expf(l0 - m) + expf(l1 - m));
        out[g * 2 + 0] = l0 - ls;
        out[g * 2 + 1] = l1 - ls;
    }
}

extern "C" void kernel_launch(void* const* d_in, const int* in_sizes, int n_in,
                              void* d_out, int out_size, void* d_ws, size_t ws_size,
                              hipStream_t stream) {
    const float* x     = (const float*)d_in[0];
    const float* W_enc = (const float*)d_in[1];
    const float* b_enc = (const float*)d_in[2];
    const float* W0    = (const float*)d_in[3];
    const float* b0    = (const float*)d_in[4];
    const float* W1a   = (const float*)d_in[5];
    const float* b1a   = (const float*)d_in[6];
    const float* W1b   = (const float*)d_in[7];
    const float* b1b   = (const float*)d_in[8];
    const float* W2a   = (const float*)d_in[9];
    const float* b2a   = (const float*)d_in[10];
    const float* W2b   = (const float*)d_in[11];
    const float* b2b   = (const float*)d_in[12];
    const float* Wf1   = (const float*)d_in[13];
    const float* bf1   = (const float*)d_in[14];
    const float* Wf2   = (const float*)d_in[15];
    const float* bf2   = (const float*)d_in[16];
    const int* src1    = (const int*)d_in[17];
    const int* dst1    = (const int*)d_in[18];
    const int* src2    = (const int*)d_in[19];
    const int* dst2    = (const int*)d_in[20];
    const int* batch   = (const int*)d_in[21];

    const size_t NB = (size_t)N_NODES * HID;   // 12.8M elements
    float* buf0 = (float*)d_ws;                // h -> x1 (in place)
    float* buf1 = buf0 + NB;                   // u  -> x2
    float* buf2 = buf1 + NB;                   // v
    unsigned* agg = (unsigned*)(buf2 + NB);    // encoded segment-max
    float* wkey  = (float*)(agg + NB);
    float* bias0 = wkey + 128;
    float* D1    = bias0 + 128;
    float* D2    = D1 + HID * HID;
    float* pooled = D2 + HID * HID;            // 128*512

    prep_kernel<<<1, 256, 0, stream>>>(W_enc, b_enc, W0, b0, W1a, W2a, wkey, bias0, D1, D2);
    encode_kernel<<<N_NODES / 2, 256, 0, stream>>>(x, W0, wkey, bias0, buf0);

    const int mmGrid = (N_NODES + 63) / 64;
    // layer 1: u1 = h@A1, v1 = h@D1 + b1a
    mm128_dual_kernel<<<mmGrid, 256, 0, stream>>>(buf0, W1a, D1, b1a, buf1, buf2, N_NODES);
    hipMemsetAsync(agg, 0, NB * sizeof(unsigned), stream);
    edge_kernel<<<1024, 256, 0, stream>>>(buf1, buf2, x, src1, dst1, W1b, W1a + 256 * HID, agg);
    combine_kernel<<<(int)(NB / 256), 256, 0, stream>>>(agg, b1b, buf0, buf0);         // x1 in place
    // layer 2
    mm128_dual_kernel<<<mmGrid, 256, 0, stream>>>(buf0, W2a, D2, b2a, buf1, buf2, N_NODES);
    hipMemsetAsync(agg, 0, NB * sizeof(unsigned), stream);
    edge_kernel<<<1024, 256, 0, stream>>>(buf1, buf2, x, src2, dst2, W2b, W2a + 256 * HID, agg);
    combine_kernel<<<(int)(NB / 256), 256, 0, stream>>>(agg, b2b, buf0, buf1);         // x2 -> buf1

    pool_kernel<<<N_GRAPHS, 256, 0, stream>>>(buf0, buf1, batch, pooled);
    final_kernel<<<N_GRAPHS, 128, 0, stream>>>(pooled, Wf1, bf1, Wf2, bf2, (float*)d_out);
}

// Round 3
// 2046.177 us; speedup vs baseline: 1.8207x; 1.6648x over previous
//
#include <hip/hip_runtime.h>
#include <cstdint>

#define N_NODES 100000
#define N_EDGES 500000
#define N_GRAPHS 128
#define HID 128

// ---- monotone float<->uint encoding for max; enc==0 marks "never written" ----
__device__ __forceinline__ unsigned encf(float f) {
    unsigned u = __float_as_uint(f);
    return (u & 0x80000000u) ? ~u : (u | 0x80000000u);
}
__device__ __forceinline__ float decf(unsigned e) {
    unsigned u = (e & 0x80000000u) ? (e & 0x7FFFFFFFu) : ~e;
    return __uint_as_float(u);
}

// ---- prep: fold key-embedding through W0; D = Wa[128:256]-Wa[0:128] ----
__global__ void prep_kernel(const float* __restrict__ W_enc, const float* __restrict__ b_enc,
                            const float* __restrict__ W0, const float* __restrict__ b0,
                            const float* __restrict__ W1a, const float* __restrict__ W2a,
                            float* __restrict__ wkey, float* __restrict__ bias0,
                            float* __restrict__ D1, float* __restrict__ D2) {
    int tid = threadIdx.x;
    if (tid < HID) {
        float wk = 0.f, bk = b0[tid];
        for (int k = 0; k < 32; ++k) {
            float w = W0[(15 + k) * HID + tid];
            wk += W_enc[k] * w;
            bk += b_enc[k] * w;
        }
        wkey[tid] = wk;
        bias0[tid] = bk;
    }
    for (int i = tid; i < HID * HID; i += blockDim.x) {
        D1[i] = W1a[HID * HID + i] - W1a[i];
        D2[i] = W2a[HID * HID + i] - W2a[i];
    }
}

// ---- encoder: h = relu(features @ W0[0:15] + key*wkey + bias0) ----
__global__ __launch_bounds__(256) void encode_kernel(const float* __restrict__ x,
                                                     const float* __restrict__ W0,
                                                     const float* __restrict__ wkey,
                                                     const float* __restrict__ bias0,
                                                     float* __restrict__ h) {
    int n = blockIdx.x * 2 + (threadIdx.x >> 7);
    int j = threadIdx.x & 127;
    const float* xr = x + n * 16;
    float acc = bias0[j] + xr[0] * wkey[j];
#pragma unroll
    for (int f = 0; f < 15; ++f)
        acc = fmaf(xr[1 + f], W0[f * HID + j], acc);
    h[n * HID + j] = fmaxf(acc, 0.f);
}

// ---- dual (N x 128) @ (128 x 128): out_u = in@Wu ; out_v = in@Wv + bv ----
__global__ __launch_bounds__(256, 4) void mm128_dual_kernel(const float* __restrict__ in,
                                                            const float* __restrict__ Wu,
                                                            const float* __restrict__ Wv,
                                                            const float* __restrict__ bv,
                                                            float* __restrict__ outu,
                                                            float* __restrict__ outv, int nrows) {
    __shared__ __align__(16) float sA[64 * 132];
    int tid = threadIdx.x;
    int n0 = blockIdx.x * 64;
#pragma unroll
    for (int q = 0; q < 8; ++q) {
        int idx = q * 256 + tid;
        int r = idx >> 5, c4 = idx & 31;
        int n = n0 + r;
        float4 vv = (n < nrows) ? ((const float4*)(in + (size_t)n * HID))[c4]
                                : make_float4(0.f, 0.f, 0.f, 0.f);
        *((float4*)(sA + r * 132 + c4 * 4)) = vv;
    }
    __syncthreads();
    int cg = tid & 15;
    int rg = tid >> 4;
#pragma unroll
    for (int pass = 0; pass < 2; ++pass) {
        const float* W = pass ? Wv : Wu;
        float* out = pass ? outv : outu;
        const float* WC = W + cg * 8;
        float acc[4][8];
#pragma unroll
        for (int r = 0; r < 4; ++r)
#pragma unroll
            for (int q = 0; q < 8; ++q) acc[r][q] = 0.f;
#pragma unroll 2
        for (int k4 = 0; k4 < 128; k4 += 4) {
            float4 a[4];
#pragma unroll
            for (int r = 0; r < 4; ++r)
                a[r] = *(const float4*)(sA + (rg * 4 + r) * 132 + k4);
#pragma unroll
            for (int kk = 0; kk < 4; ++kk) {
                const float4* wr = (const float4*)(WC + (k4 + kk) * HID);
                float4 w0 = wr[0], w1 = wr[1];
#pragma unroll
                for (int r = 0; r < 4; ++r) {
                    float av = ((const float*)&a[r])[kk];
                    acc[r][0] = fmaf(av, w0.x, acc[r][0]);
                    acc[r][1] = fmaf(av, w0.y, acc[r][1]);
                    acc[r][2] = fmaf(av, w0.z, acc[r][2]);
                    acc[r][3] = fmaf(av, w0.w, acc[r][3]);
                    acc[r][4] = fmaf(av, w1.x, acc[r][4]);
                    acc[r][5] = fmaf(av, w1.y, acc[r][5]);
                    acc[r][6] = fmaf(av, w1.z, acc[r][6]);
                    acc[r][7] = fmaf(av, w1.w, acc[r][7]);
                }
            }
        }
        float bvv[8];
#pragma unroll
        for (int q = 0; q < 8; ++q) bvv[q] = pass ? bv[cg * 8 + q] : 0.f;
#pragma unroll
        for (int r = 0; r < 4; ++r) {
            int n = n0 + rg * 4 + r;
            if (n < nrows) {
                float4 o0 = make_float4(acc[r][0] + bvv[0], acc[r][1] + bvv[1],
                                        acc[r][2] + bvv[2], acc[r][3] + bvv[3]);
                float4 o1 = make_float4(acc[r][4] + bvv[4], acc[r][5] + bvv[5],
                                        acc[r][6] + bvv[6], acc[r][7] + bvv[7]);
                float4* op = (float4*)(out + (size_t)n * HID + cg * 8);
                op[0] = o0;
                op[1] = o1;
            }
        }
    }
}

// ---- CSR build: histogram -> scan -> scatter (counting sort by dst) ----
__global__ __launch_bounds__(256) void hist_kernel(const int* __restrict__ dst, int* __restrict__ cnt) {
    int e = blockIdx.x * 256 + threadIdx.x;
    if (e < N_EDGES) atomicAdd(&cnt[dst[e]], 1);
}

// single block of 1024 threads; each thread owns a span of 98 nodes
__global__ __launch_bounds__(1024) void scan_kernel(const int* __restrict__ cnt, int* __restrict__ cursor) {
    __shared__ int part[1024];
    int tid = threadIdx.x;
    const int SPAN = (N_NODES + 1023) / 1024;   // 98
    int base = tid * SPAN;
    int s = 0;
    for (int i = 0; i < SPAN; ++i) {
        int idx = base + i;
        if (idx < N_NODES) s += cnt[idx];
    }
    part[tid] = s;
    __syncthreads();
    for (int off = 1; off < 1024; off <<= 1) {
        int v = (tid >= off) ? part[tid - off] : 0;
        __syncthreads();
        part[tid] += v;
        __syncthreads();
    }
    int run = (tid > 0) ? part[tid - 1] : 0;    // exclusive prefix at span start
    for (int i = 0; i < SPAN; ++i) {
        int idx = base + i;
        if (idx < N_NODES) {
            cursor[idx] = run;
            run += cnt[idx];
        }
    }
}

__global__ __launch_bounds__(256) void scatter_kernel(const int* __restrict__ src,
                                                      const int* __restrict__ dst,
                                                      int* __restrict__ cursor,
                                                      int* __restrict__ psrc,
                                                      int* __restrict__ pdst) {
    int e = blockIdx.x * 256 + threadIdx.x;
    if (e < N_EDGES) {
        int d = dst[e];
        int pos = atomicAdd(&cursor[d], 1);
        psrc[pos] = src[e];
        pdst[pos] = d;
    }
}

// ---- edge conv v3: dst-sorted windows of 32 edges, segmented max, atomics only
//      for runs touching a window boundary (~2 dsts per window) ----
__global__ __launch_bounds__(256) void edge_kernel(const float* __restrict__ u,
                                                   const float* __restrict__ v,
                                                   const float* __restrict__ x,
                                                   const int* __restrict__ psrc,
                                                   const int* __restrict__ pdst,
                                                   const float* __restrict__ Wb,
                                                   const float* __restrict__ wlast,
                                                   unsigned* __restrict__ agg) {
    __shared__ __align__(16) float sT[32 * 132];   // t, then reused for msg
    __shared__ int sSrc[32], sDst[32];
    __shared__ float sKd[32];
    __shared__ int sPrev, sNext;
    int tid = threadIdx.x;
    int w0 = blockIdx.x * 32;

    if (tid < 32) {
        int s = psrc[w0 + tid], d = pdst[w0 + tid];
        sSrc[tid] = s;
        sDst[tid] = d;
        sKd[tid] = x[(size_t)s * 16] - x[(size_t)d * 16];
    }
    if (tid == 32) sPrev = (w0 > 0) ? pdst[w0 - 1] : -1;
    if (tid == 33) sNext = (w0 + 32 < N_EDGES) ? pdst[w0 + 32] : -1;
    __syncthreads();

    // phase 1: t = leaky(u[src]+v[dst]+kd*w256)  (8 threads per edge, 16 floats each)
    {
        int eloc = tid >> 3;
        int kb = (tid & 7) << 4;
        int s = sSrc[eloc], d = sDst[eloc];
        float kd = sKd[eloc];
        const float4* ur = (const float4*)(u + (size_t)s * HID + kb);
        const float4* vr = (const float4*)(v + (size_t)d * HID + kb);
        const float4* wr = (const float4*)(wlast + kb);
        float4* trow = (float4*)(sT + eloc * 132 + kb);
#pragma unroll
        for (int q = 0; q < 4; ++q) {
            float4 uu = ur[q], vv = vr[q], ww = wr[q];
            float4 p4;
            p4.x = fmaf(kd, ww.x, uu.x + vv.x);
            p4.y = fmaf(kd, ww.y, uu.y + vv.y);
            p4.z = fmaf(kd, ww.z, uu.z + vv.z);
            p4.w = fmaf(kd, ww.w, uu.w + vv.w);
            p4.x = p4.x > 0.f ? p4.x : 0.1f * p4.x;
            p4.y = p4.y > 0.f ? p4.y : 0.1f * p4.y;
            p4.z = p4.z > 0.f ? p4.z : 0.1f * p4.z;
            p4.w = p4.w > 0.f ? p4.w : 0.1f * p4.w;
            trow[q] = p4;
        }
    }
    __syncthreads();

    // phase 2: msg = t @ Wb  (weights from global, 16-way broadcast-coalesced)
    int cg = tid & 15;        // cols cg*8..+7
    int eg = tid >> 4;        // edges 2eg, 2eg+1
    int e0 = eg * 2, e1 = e0 + 1;
    const float* t0p = sT + e0 * 132;
    const float* t1p = sT + e1 * 132;
    const float* WC = Wb + cg * 8;
    float acc0[8], acc1[8];
#pragma unroll
    for (int q = 0; q < 8; ++q) { acc0[q] = 0.f; acc1[q] = 0.f; }
#pragma unroll 2
    for (int k4 = 0; k4 < 128; k4 += 4) {
        float4 t0 = *(const float4*)(t0p + k4);
        float4 t1 = *(const float4*)(t1p + k4);
#pragma unroll
        for (int kk = 0; kk < 4; ++kk) {
            const float4* wr = (const float4*)(WC + (k4 + kk) * HID);
            float4 w0 = wr[0], w1 = wr[1];
            float a0 = ((const float*)&t0)[kk];
            float a1 = ((const float*)&t1)[kk];
            acc0[0] = fmaf(a0, w0.x, acc0[0]);
            acc0[1] = fmaf(a0, w0.y, acc0[1]);
            acc0[2] = fmaf(a0, w0.z, acc0[2]);
            acc0[3] = fmaf(a0, w0.w, acc0[3]);
            acc0[4] = fmaf(a0, w1.x, acc0[4]);
            acc0[5] = fmaf(a0, w1.y, acc0[5]);
            acc0[6] = fmaf(a0, w1.z, acc0[6]);
            acc0[7] = fmaf(a0, w1.w, acc0[7]);
            acc1[0] = fmaf(a1, w0.x, acc1[0]);
            acc1[1] = fmaf(a1, w0.y, acc1[1]);
            acc1[2] = fmaf(a1, w0.z, acc1[2]);
            acc1[3] = fmaf(a1, w0.w, acc1[3]);
            acc1[4] = fmaf(a1, w1.x, acc1[4]);
            acc1[5] = fmaf(a1, w1.y, acc1[5]);
            acc1[6] = fmaf(a1, w1.z, acc1[6]);
            acc1[7] = fmaf(a1, w1.w, acc1[7]);
        }
    }
    __syncthreads();   // all reads of t done -> safe to overwrite sT with msg

    {
        float4* m0 = (float4*)(sT + e0 * 132 + cg * 8);
        float4* m1 = (float4*)(sT + e1 * 132 + cg * 8);
        m0[0] = make_float4(acc0[0], acc0[1], acc0[2], acc0[3]);
        m0[1] = make_float4(acc0[4], acc0[5], acc0[6], acc0[7]);
        m1[0] = make_float4(acc1[0], acc1[1], acc1[2], acc1[3]);
        m1[1] = make_float4(acc1[4], acc1[5], acc1[6], acc1[7]);
    }
    __syncthreads();

    // phase 3: segmented max over dst runs; plain store for interior runs,
    // atomicMax only when the run touches a window boundary.
    if (tid < 128) {
        int j = tid;
        int prevD = sPrev, nextD = sNext;
        int cur = sDst[0], rs = 0;
        float mx = sT[0 * 132 + j];
        for (int e = 1; e < 32; ++e) {
            int d = sDst[e];               // wave-uniform
            float vv = sT[e * 132 + j];
            if (d != cur) {
                unsigned en = encf(mx);
                unsigned* ap = agg + (size_t)cur * HID + j;
                if (rs == 0 && cur == prevD) atomicMax(ap, en);
                else *ap = en;
                cur = d; rs = e; mx = vv;
            } else {
                mx = fmaxf(mx, vv);
            }
        }
        unsigned en = encf(mx);
        unsigned* ap = agg + (size_t)cur * HID + j;
        if ((rs == 0 && cur == prevD) || cur == nextD) atomicMax(ap, en);
        else *ap = en;
    }
}

// ---- combine: out = relu((agg? dec(agg)+bb : 0) + base) ----
__global__ __launch_bounds__(256) void combine_kernel(const unsigned* __restrict__ agg,
                                                      const float* __restrict__ bb,
                                                      const float* __restrict__ base,
                                                      float* __restrict__ out) {
    size_t i = (size_t)blockIdx.x * 256 + threadIdx.x;
    unsigned e = agg[i];
    int j = (int)(i & 127);
    float val = (e == 0u) ? 0.f : (decf(e) + bb[j]);
    out[i] = fmaxf(val + base[i], 0.f);
}

// ---- pooling: batch sorted; one block per graph ----
__global__ __launch_bounds__(256) void pool_kernel(const float* __restrict__ x1,
                                                   const float* __restrict__ x2,
                                                   const int* __restrict__ batch,
                                                   float* __restrict__ pooled) {
    int g = blockIdx.x;
    int tid = threadIdx.x;
    int lo = 0, hi = N_NODES;
    while (lo < hi) { int mid = (lo + hi) >> 1; if (batch[mid] < g) lo = mid + 1; else hi = mid; }
    int start = lo;
    hi = N_NODES;
    while (lo < hi) { int mid = (lo + hi) >> 1; if (batch[mid] < g + 1) lo = mid + 1; else hi = mid; }
    int end = lo;
    const float* srcp = (tid < 128) ? (x1 + tid) : (x2 + (tid - 128));
    float mx = -INFINITY, sm = 0.f;
#pragma unroll 4
    for (int n = start; n < end; ++n) {
        float vv = srcp[(size_t)n * HID];
        mx = fmaxf(mx, vv);
        sm += vv;
    }
    int cnt = end - start;
    pooled[(size_t)g * 512 + tid] = cnt ? mx : 0.f;
    pooled[(size_t)g * 512 + 256 + tid] = sm / (float)(cnt > 1 ? cnt : 1);
}

// ---- final MLP + log_softmax ----
__global__ __launch_bounds__(128) void final_kernel(const float* __restrict__ pooled,
                                                    const float* __restrict__ Wf1,
                                                    const float* __restrict__ bf1,
                                                    const float* __restrict__ Wf2,
                                                    const float* __restrict__ bf2,
                                                    float* __restrict__ out) {
    __shared__ float sP[512];
    __shared__ float sH[128];
    int g = blockIdx.x, tid = threadIdx.x;
#pragma unroll
    for (int q = 0; q < 4; ++q) sP[q * 128 + tid] = pooled[(size_t)g * 512 + q * 128 + tid];
    __syncthreads();
    float acc = bf1[tid];
    for (int k = 0; k < 512; ++k) acc = fmaf(sP[k], Wf1[k * HID + tid], acc);
    sH[tid] = fmaxf(acc, 0.f);
    __syncthreads();
    if (tid < 2) {
        float l = bf2[tid];
        for (int k = 0; k < 128; ++k) l = fmaf(sH[k], Wf2[k * 2 + tid], l);
        sP[tid] = l;
    }
    __syncthreads();
    if (tid == 0) {
        float l0 = sP[0], l1 = sP[1];
        float m = fmaxf(l0, l1);
        float ls = m + logf(expf(l0 - m) + expf(l1 - m));
        out[g * 2 + 0] = l0 - ls;
        out[g * 2 + 1] = l1 - ls;
    }
}

extern "C" void kernel_launch(void* const* d_in, const int* in_sizes, int n_in,
                              void* d_out, int out_size, void* d_ws, size_t ws_size,
                              hipStream_t stream) {
    const float* x     = (const float*)d_in[0];
    const float* W_enc = (const float*)d_in[1];
    const float* b_enc = (const float*)d_in[2];
    const float* W0    = (const float*)d_in[3];
    const float* b0    = (const float*)d_in[4];
    const float* W1a   = (const float*)d_in[5];
    const float* b1a   = (const float*)d_in[6];
    const float* W1b   = (const float*)d_in[7];
    const float* b1b   = (const float*)d_in[8];
    const float* W2a   = (const float*)d_in[9];
    const float* b2a   = (const float*)d_in[10];
    const float* W2b   = (const float*)d_in[11];
    const float* b2b   = (const float*)d_in[12];
    const float* Wf1   = (const float*)d_in[13];
    const float* bf1   = (const float*)d_in[14];
    const float* Wf2   = (const float*)d_in[15];
    const float* bf2   = (const float*)d_in[16];
    const int* src1    = (const int*)d_in[17];
    const int* dst1    = (const int*)d_in[18];
    const int* src2    = (const int*)d_in[19];
    const int* dst2    = (const int*)d_in[20];
    const int* batch   = (const int*)d_in[21];

    const size_t NB = (size_t)N_NODES * HID;   // 12.8M elements
    float* buf0 = (float*)d_ws;                // h -> x1 (in place)
    float* buf1 = buf0 + NB;                   // u  -> x2
    float* buf2 = buf1 + NB;                   // v
    unsigned* agg = (unsigned*)(buf2 + NB);    // encoded segment-max
    float* wkey  = (float*)(agg + NB);
    float* bias0 = wkey + 128;
    float* D1    = bias0 + 128;
    float* D2    = D1 + HID * HID;
    float* pooled = D2 + HID * HID;            // 128*512
    int* cnt    = (int*)(pooled + 128 * 512);  // 100000
    int* cursor = cnt + N_NODES;               // 100000
    int* psrc   = cursor + N_NODES;            // 500000
    int* pdst   = psrc + N_EDGES;              // 500000

    const int histGrid = (N_EDGES + 255) / 256;
    const int edgeGrid = N_EDGES / 32;         // 15625 windows
    const int mmGrid = (N_NODES + 63) / 64;

    prep_kernel<<<1, 256, 0, stream>>>(W_enc, b_enc, W0, b0, W1a, W2a, wkey, bias0, D1, D2);
    encode_kernel<<<N_NODES / 2, 256, 0, stream>>>(x, W0, wkey, bias0, buf0);

    // ---- layer 1 ----
    hipMemsetAsync(cnt, 0, N_NODES * sizeof(int), stream);
    hist_kernel<<<histGrid, 256, 0, stream>>>(dst1, cnt);
    scan_kernel<<<1, 1024, 0, stream>>>(cnt, cursor);
    scatter_kernel<<<histGrid, 256, 0, stream>>>(src1, dst1, cursor, psrc, pdst);
    mm128_dual_kernel<<<mmGrid, 256, 0, stream>>>(buf0, W1a, D1, b1a, buf1, buf2, N_NODES);
    hipMemsetAsync(agg, 0, NB * sizeof(unsigned), stream);
    edge_kernel<<<edgeGrid, 256, 0, stream>>>(buf1, buf2, x, psrc, pdst, W1b, W1a + 256 * HID, agg);
    combine_kernel<<<(int)(NB / 256), 256, 0, stream>>>(agg, b1b, buf0, buf0);   // x1 in place

    // ---- layer 2 ----
    hipMemsetAsync(cnt, 0, N_NODES * sizeof(int), stream);
    hist_kernel<<<histGrid, 256, 0, stream>>>(dst2, cnt);
    scan_kernel<<<1, 1024, 0, stream>>>(cnt, cursor);
    scatter_kernel<<<histGrid, 256, 0, stream>>>(src2, dst2, cursor, psrc, pdst);
    mm128_dual_kernel<<<mmGrid, 256, 0, stream>>>(buf0, W2a, D2, b2a, buf1, buf2, N_NODES);
    hipMemsetAsync(agg, 0, NB * sizeof(unsigned), stream);
    edge_kernel<<<edgeGrid, 256, 0, stream>>>(buf1, buf2, x, psrc, pdst, W2b, W2a + 256 * HID, agg);
    combine_kernel<<<(int)(NB / 256), 256, 0, stream>>>(agg, b2b, buf0, buf1);   // x2 -> buf1

    pool_kernel<<<N_GRAPHS, 256, 0, stream>>>(buf0, buf1, batch, pooled);
    final_kernel<<<N_GRAPHS, 128, 0, stream>>>(pooled, Wf1, bf1, Wf2, bf2, (float*)d_out);
}

// Round 4
// 1728.245 us; speedup vs baseline: 2.1557x; 1.1840x over previous
//
#include <hip/hip_runtime.h>
#include <cstdint>

#define N_NODES 100000
#define N_EDGES 500000
#define N_GRAPHS 128
#define HID 128

// ---- monotone float<->uint encoding for max; enc==0 marks "never written" ----
__device__ __forceinline__ unsigned encf(float f) {
    unsigned u = __float_as_uint(f);
    return (u & 0x80000000u) ? ~u : (u | 0x80000000u);
}
__device__ __forceinline__ float decf(unsigned e) {
    unsigned u = (e & 0x80000000u) ? (e & 0x7FFFFFFFu) : ~e;
    return __uint_as_float(u);
}

// ---- prep: fold key-embedding through W0; D = Wa[128:256]-Wa[0:128] ----
__global__ void prep_kernel(const float* __restrict__ W_enc, const float* __restrict__ b_enc,
                            const float* __restrict__ W0, const float* __restrict__ b0,
                            const float* __restrict__ W1a, const float* __restrict__ W2a,
                            float* __restrict__ wkey, float* __restrict__ bias0,
                            float* __restrict__ D1, float* __restrict__ D2) {
    int tid = threadIdx.x;
    if (tid < HID) {
        float wk = 0.f, bk = b0[tid];
        for (int k = 0; k < 32; ++k) {
            float w = W0[(15 + k) * HID + tid];
            wk += W_enc[k] * w;
            bk += b_enc[k] * w;
        }
        wkey[tid] = wk;
        bias0[tid] = bk;
    }
    for (int i = tid; i < HID * HID; i += blockDim.x) {
        D1[i] = W1a[HID * HID + i] - W1a[i];
        D2[i] = W2a[HID * HID + i] - W2a[i];
    }
}

// ---- encoder: h = relu(features @ W0[0:15] + key*wkey + bias0) ----
__global__ __launch_bounds__(256) void encode_kernel(const float* __restrict__ x,
                                                     const float* __restrict__ W0,
                                                     const float* __restrict__ wkey,
                                                     const float* __restrict__ bias0,
                                                     float* __restrict__ h) {
    int n = blockIdx.x * 2 + (threadIdx.x >> 7);
    int j = threadIdx.x & 127;
    const float* xr = x + n * 16;
    float acc = bias0[j] + xr[0] * wkey[j];
#pragma unroll
    for (int f = 0; f < 15; ++f)
        acc = fmaf(xr[1 + f], W0[f * HID + j], acc);
    h[n * HID + j] = fmaxf(acc, 0.f);
}

// ---- dual (N x 128) @ (128 x 128): out_u = in@Wu ; out_v = in@Wv + bv ----
__global__ __launch_bounds__(256, 4) void mm128_dual_kernel(const float* __restrict__ in,
                                                            const float* __restrict__ Wu,
                                                            const float* __restrict__ Wv,
                                                            const float* __restrict__ bv,
                                                            float* __restrict__ outu,
                                                            float* __restrict__ outv, int nrows) {
    __shared__ __align__(16) float sA[64 * 132];
    int tid = threadIdx.x;
    int n0 = blockIdx.x * 64;
#pragma unroll
    for (int q = 0; q < 8; ++q) {
        int idx = q * 256 + tid;
        int r = idx >> 5, c4 = idx & 31;
        int n = n0 + r;
        float4 vv = (n < nrows) ? ((const float4*)(in + (size_t)n * HID))[c4]
                                : make_float4(0.f, 0.f, 0.f, 0.f);
        *((float4*)(sA + r * 132 + c4 * 4)) = vv;
    }
    __syncthreads();
    int cg = tid & 15;
    int rg = tid >> 4;
#pragma unroll
    for (int pass = 0; pass < 2; ++pass) {
        const float* W = pass ? Wv : Wu;
        float* out = pass ? outv : outu;
        const float* WC = W + cg * 8;
        float acc[4][8];
#pragma unroll
        for (int r = 0; r < 4; ++r)
#pragma unroll
            for (int q = 0; q < 8; ++q) acc[r][q] = 0.f;
#pragma unroll 2
        for (int k4 = 0; k4 < 128; k4 += 4) {
            float4 a[4];
#pragma unroll
            for (int r = 0; r < 4; ++r)
                a[r] = *(const float4*)(sA + (rg * 4 + r) * 132 + k4);
#pragma unroll
            for (int kk = 0; kk < 4; ++kk) {
                const float4* wr = (const float4*)(WC + (k4 + kk) * HID);
                float4 w0 = wr[0], w1 = wr[1];
#pragma unroll
                for (int r = 0; r < 4; ++r) {
                    float av = ((const float*)&a[r])[kk];
                    acc[r][0] = fmaf(av, w0.x, acc[r][0]);
                    acc[r][1] = fmaf(av, w0.y, acc[r][1]);
                    acc[r][2] = fmaf(av, w0.z, acc[r][2]);
                    acc[r][3] = fmaf(av, w0.w, acc[r][3]);
                    acc[r][4] = fmaf(av, w1.x, acc[r][4]);
                    acc[r][5] = fmaf(av, w1.y, acc[r][5]);
                    acc[r][6] = fmaf(av, w1.z, acc[r][6]);
                    acc[r][7] = fmaf(av, w1.w, acc[r][7]);
                }
            }
        }
        float bvv[8];
#pragma unroll
        for (int q = 0; q < 8; ++q) bvv[q] = pass ? bv[cg * 8 + q] : 0.f;
#pragma unroll
        for (int r = 0; r < 4; ++r) {
            int n = n0 + rg * 4 + r;
            if (n < nrows) {
                float4 o0 = make_float4(acc[r][0] + bvv[0], acc[r][1] + bvv[1],
                                        acc[r][2] + bvv[2], acc[r][3] + bvv[3]);
                float4 o1 = make_float4(acc[r][4] + bvv[4], acc[r][5] + bvv[5],
                                        acc[r][6] + bvv[6], acc[r][7] + bvv[7]);
                float4* op = (float4*)(out + (size_t)n * HID + cg * 8);
                op[0] = o0;
                op[1] = o1;
            }
        }
    }
}

// ---- CSR build: histogram -> scan -> scatter (counting sort by dst) ----
__global__ __launch_bounds__(256) void hist_kernel(const int* __restrict__ dst, int* __restrict__ cnt) {
    int e = blockIdx.x * 256 + threadIdx.x;
    if (e < N_EDGES) atomicAdd(&cnt[dst[e]], 1);
}

__global__ __launch_bounds__(1024) void scan_kernel(const int* __restrict__ cnt, int* __restrict__ cursor) {
    __shared__ int part[1024];
    int tid = threadIdx.x;
    const int SPAN = (N_NODES + 1023) / 1024;   // 98
    int base = tid * SPAN;
    int s = 0;
    for (int i = 0; i < SPAN; ++i) {
        int idx = base + i;
        if (idx < N_NODES) s += cnt[idx];
    }
    part[tid] = s;
    __syncthreads();
    for (int off = 1; off < 1024; off <<= 1) {
        int v = (tid >= off) ? part[tid - off] : 0;
        __syncthreads();
        part[tid] += v;
        __syncthreads();
    }
    int run = (tid > 0) ? part[tid - 1] : 0;
    for (int i = 0; i < SPAN; ++i) {
        int idx = base + i;
        if (idx < N_NODES) {
            cursor[idx] = run;
            run += cnt[idx];
        }
    }
}

__global__ __launch_bounds__(256) void scatter_kernel(const int* __restrict__ src,
                                                      const int* __restrict__ dst,
                                                      int* __restrict__ cursor,
                                                      int* __restrict__ psrc,
                                                      int* __restrict__ pdst) {
    int e = blockIdx.x * 256 + threadIdx.x;
    if (e < N_EDGES) {
        int d = dst[e];
        int pos = atomicAdd(&cursor[d], 1);
        psrc[pos] = src[e];
        pdst[pos] = d;
    }
}

// ---- edge conv v4: 64-edge dst-sorted windows, 4 edges x 8 cols per thread ----
// Weight traffic halved vs v3 (8 KB/edge). Tail handled by clamping (max idempotent).
__global__ __launch_bounds__(256, 4) void edge_kernel(const float* __restrict__ u,
                                                      const float* __restrict__ v,
                                                      const float* __restrict__ x,
                                                      const int* __restrict__ psrc,
                                                      const int* __restrict__ pdst,
                                                      const float* __restrict__ Wb,
                                                      const float* __restrict__ wlast,
                                                      unsigned* __restrict__ agg) {
    __shared__ __align__(16) float sT[64 * 132];   // t, then reused for msg (33.8 KB)
    __shared__ int sSrc[64], sDst[64];
    __shared__ float sKd[64];
    __shared__ int sPrev, sNext;
    int tid = threadIdx.x;
    int w0 = blockIdx.x * 64;

    if (tid < 64) {
        int e = w0 + tid;
        if (e >= N_EDGES) e = N_EDGES - 1;     // clamp: duplicate of last edge, idempotent under max
        int s = psrc[e], d = pdst[e];
        sSrc[tid] = s;
        sDst[tid] = d;
        sKd[tid] = x[(size_t)s * 16] - x[(size_t)d * 16];
    }
    if (tid == 64) sPrev = (w0 > 0) ? pdst[w0 - 1] : -1;
    if (tid == 65) sNext = (w0 + 64 < N_EDGES) ? pdst[w0 + 64] : -1;
    __syncthreads();

    // phase 1: t = leaky(u[src]+v[dst]+kd*w256)  (4 threads/edge, 32 floats each)
    {
        int eloc = tid >> 2;            // 0..63
        int kb = (tid & 3) << 5;        // 0,32,64,96
        int s = sSrc[eloc], d = sDst[eloc];
        float kd = sKd[eloc];
        const float4* ur = (const float4*)(u + (size_t)s * HID + kb);
        const float4* vr = (const float4*)(v + (size_t)d * HID + kb);
        const float4* wr = (const float4*)(wlast + kb);
        float4 uu[8], vv[8];
#pragma unroll
        for (int q = 0; q < 8; ++q) uu[q] = ur[q];
#pragma unroll
        for (int q = 0; q < 8; ++q) vv[q] = vr[q];
        float4* trow = (float4*)(sT + eloc * 132 + kb);
#pragma unroll
        for (int q = 0; q < 8; ++q) {
            float4 ww = wr[q];
            float4 p4;
            p4.x = fmaf(kd, ww.x, uu[q].x + vv[q].x);
            p4.y = fmaf(kd, ww.y, uu[q].y + vv[q].y);
            p4.z = fmaf(kd, ww.z, uu[q].z + vv[q].z);
            p4.w = fmaf(kd, ww.w, uu[q].w + vv[q].w);
            p4.x = p4.x > 0.f ? p4.x : 0.1f * p4.x;
            p4.y = p4.y > 0.f ? p4.y : 0.1f * p4.y;
            p4.z = p4.z > 0.f ? p4.z : 0.1f * p4.z;
            p4.w = p4.w > 0.f ? p4.w : 0.1f * p4.w;
            trow[q] = p4;
        }
    }
    __syncthreads();

    // phase 2: msg = t @ Wb, 4 edges x 8 cols per thread
    int cg = tid & 15;        // cols cg*8..+7
    int eg = tid >> 4;        // edge group: edges eg*4..+3
    int eb = eg * 4;
    const float* WC = Wb + cg * 8;
    float acc[4][8];
#pragma unroll
    for (int r = 0; r < 4; ++r)
#pragma unroll
        for (int q = 0; q < 8; ++q) acc[r][q] = 0.f;
#pragma unroll 2
    for (int k4 = 0; k4 < 128; k4 += 4) {
        float4 t[4];
#pragma unroll
        for (int r = 0; r < 4; ++r)
            t[r] = *(const float4*)(sT + (eb + r) * 132 + k4);
#pragma unroll
        for (int kk = 0; kk < 4; ++kk) {
            const float4* wr = (const float4*)(WC + (k4 + kk) * HID);
            float4 w0 = wr[0], w1 = wr[1];
#pragma unroll
            for (int r = 0; r < 4; ++r) {
                float av = ((const float*)&t[r])[kk];
                acc[r][0] = fmaf(av, w0.x, acc[r][0]);
                acc[r][1] = fmaf(av, w0.y, acc[r][1]);
                acc[r][2] = fmaf(av, w0.z, acc[r][2]);
                acc[r][3] = fmaf(av, w0.w, acc[r][3]);
                acc[r][4] = fmaf(av, w1.x, acc[r][4]);
                acc[r][5] = fmaf(av, w1.y, acc[r][5]);
                acc[r][6] = fmaf(av, w1.z, acc[r][6]);
                acc[r][7] = fmaf(av, w1.w, acc[r][7]);
            }
        }
    }
    __syncthreads();   // reads of t done -> safe to overwrite sT with msg

#pragma unroll
    for (int r = 0; r < 4; ++r) {
        float4* mp = (float4*)(sT + (eb + r) * 132 + cg * 8);
        mp[0] = make_float4(acc[r][0], acc[r][1], acc[r][2], acc[r][3]);
        mp[1] = make_float4(acc[r][4], acc[r][5], acc[r][6], acc[r][7]);
    }
    __syncthreads();

    // phase 3: segmented max, 2 threads per column (half-window each);
    // runs touching any boundary (block or half) -> atomicMax, else plain store.
    {
        int j = tid & 127;
        int h = tid >> 7;            // 0 or 1
        int eBeg = h * 32, eEnd = eBeg + 32;
        int prevD = (h == 0) ? sPrev : sDst[31];
        int nextD = (h == 0) ? sDst[32] : sNext;
        int cur = sDst[eBeg], rs = eBeg;
        float mx = sT[eBeg * 132 + j];
        for (int e = eBeg + 1; e < eEnd; ++e) {
            int d = sDst[e];               // uniform within the half's lanes
            float vv = sT[e * 132 + j];
            if (d != cur) {
                unsigned en = encf(mx);
                unsigned* ap = agg + (size_t)cur * HID + j;
                if (rs == eBeg && cur == prevD) atomicMax(ap, en);
                else *ap = en;
                cur = d; rs = e; mx = vv;
            } else {
                mx = fmaxf(mx, vv);
            }
        }
        unsigned en = encf(mx);
        unsigned* ap = agg + (size_t)cur * HID + j;
        if ((rs == eBeg && cur == prevD) || cur == nextD) atomicMax(ap, en);
        else *ap = en;
    }
}

// ---- combine: out = relu((agg? dec(agg)+bb : 0) + base) ----
__global__ __launch_bounds__(256) void combine_kernel(const unsigned* __restrict__ agg,
                                                      const float* __restrict__ bb,
                                                      const float* __restrict__ base,
                                                      float* __restrict__ out) {
    size_t i = (size_t)blockIdx.x * 256 + threadIdx.x;
    unsigned e = agg[i];
    int j = (int)(i & 127);
    float val = (e == 0u) ? 0.f : (decf(e) + bb[j]);
    out[i] = fmaxf(val + base[i], 0.f);
}

// ---- pooling: batch sorted; one block per graph ----
__global__ __launch_bounds__(256) void pool_kernel(const float* __restrict__ x1,
                                                   const float* __restrict__ x2,
                                                   const int* __restrict__ batch,
                                                   float* __restrict__ pooled) {
    int g = blockIdx.x;
    int tid = threadIdx.x;
    int lo = 0, hi = N_NODES;
    while (lo < hi) { int mid = (lo + hi) >> 1; if (batch[mid] < g) lo = mid + 1; else hi = mid; }
    int start = lo;
    hi = N_NODES;
    while (lo < hi) { int mid = (lo + hi) >> 1; if (batch[mid] < g + 1) lo = mid + 1; else hi = mid; }
    int end = lo;
    const float* srcp = (tid < 128) ? (x1 + tid) : (x2 + (tid - 128));
    float mx = -INFINITY, sm = 0.f;
#pragma unroll 4
    for (int n = start; n < end; ++n) {
        float vv = srcp[(size_t)n * HID];
        mx = fmaxf(mx, vv);
        sm += vv;
    }
    int cnt = end - start;
    pooled[(size_t)g * 512 + tid] = cnt ? mx : 0.f;
    pooled[(size_t)g * 512 + 256 + tid] = sm / (float)(cnt > 1 ? cnt : 1);
}

// ---- final MLP + log_softmax ----
__global__ __launch_bounds__(128) void final_kernel(const float* __restrict__ pooled,
                                                    const float* __restrict__ Wf1,
                                                    const float* __restrict__ bf1,
                                                    const float* __restrict__ Wf2,
                                                    const float* __restrict__ bf2,
                                                    float* __restrict__ out) {
    __shared__ float sP[512];
    __shared__ float sH[128];
    int g = blockIdx.x, tid = threadIdx.x;
#pragma unroll
    for (int q = 0; q < 4; ++q) sP[q * 128 + tid] = pooled[(size_t)g * 512 + q * 128 + tid];
    __syncthreads();
    float acc = bf1[tid];
    for (int k = 0; k < 512; ++k) acc = fmaf(sP[k], Wf1[k * HID + tid], acc);
    sH[tid] = fmaxf(acc, 0.f);
    __syncthreads();
    if (tid < 2) {
        float l = bf2[tid];
        for (int k = 0; k < 128; ++k) l = fmaf(sH[k], Wf2[k * 2 + tid], l);
        sP[tid] = l;
    }
    __syncthreads();
    if (tid == 0) {
        float l0 = sP[0], l1 = sP[1];
        float m = fmaxf(l0, l1);
        float ls = m + logf(expf(l0 - m) + expf(l1 - m));
        out[g * 2 + 0] = l0 - ls;
        out[g * 2 + 1] = l1 - ls;
    }
}

extern "C" void kernel_launch(void* const* d_in, const int* in_sizes, int n_in,
                              void* d_out, int out_size, void* d_ws, size_t ws_size,
                              hipStream_t stream) {
    const float* x     = (const float*)d_in[0];
    const float* W_enc = (const float*)d_in[1];
    const float* b_enc = (const float*)d_in[2];
    const float* W0    = (const float*)d_in[3];
    const float* b0    = (const float*)d_in[4];
    const float* W1a   = (const float*)d_in[5];
    const float* b1a   = (const float*)d_in[6];
    const float* W1b   = (const float*)d_in[7];
    const float* b1b   = (const float*)d_in[8];
    const float* W2a   = (const float*)d_in[9];
    const float* b2a   = (const float*)d_in[10];
    const float* W2b   = (const float*)d_in[11];
    const float* b2b   = (const float*)d_in[12];
    const float* Wf1   = (const float*)d_in[13];
    const float* bf1   = (const float*)d_in[14];
    const float* Wf2   = (const float*)d_in[15];
    const float* bf2   = (const float*)d_in[16];
    const int* src1    = (const int*)d_in[17];
    const int* dst1    = (const int*)d_in[18];
    const int* src2    = (const int*)d_in[19];
    const int* dst2    = (const int*)d_in[20];
    const int* batch   = (const int*)d_in[21];

    const size_t NB = (size_t)N_NODES * HID;   // 12.8M elements
    float* buf0 = (float*)d_ws;                // h -> x1 (in place)
    float* buf1 = buf0 + NB;                   // u  -> x2
    float* buf2 = buf1 + NB;                   // v
    unsigned* agg = (unsigned*)(buf2 + NB);    // encoded segment-max
    float* wkey  = (float*)(agg + NB);
    float* bias0 = wkey + 128;
    float* D1    = bias0 + 128;
    float* D2    = D1 + HID * HID;
    float* pooled = D2 + HID * HID;            // 128*512
    int* cnt    = (int*)(pooled + 128 * 512);  // 100000
    int* cursor = cnt + N_NODES;               // 100000
    int* psrc   = cursor + N_NODES;            // 500000
    int* pdst   = psrc + N_EDGES;              // 500000

    const int histGrid = (N_EDGES + 255) / 256;
    const int edgeGrid = (N_EDGES + 63) / 64;  // 7813 windows of 64
    const int mmGrid = (N_NODES + 63) / 64;

    prep_kernel<<<1, 256, 0, stream>>>(W_enc, b_enc, W0, b0, W1a, W2a, wkey, bias0, D1, D2);
    encode_kernel<<<N_NODES / 2, 256, 0, stream>>>(x, W0, wkey, bias0, buf0);

    // ---- layer 1 ----
    hipMemsetAsync(cnt, 0, N_NODES * sizeof(int), stream);
    hist_kernel<<<histGrid, 256, 0, stream>>>(dst1, cnt);
    scan_kernel<<<1, 1024, 0, stream>>>(cnt, cursor);
    scatter_kernel<<<histGrid, 256, 0, stream>>>(src1, dst1, cursor, psrc, pdst);
    mm128_dual_kernel<<<mmGrid, 256, 0, stream>>>(buf0, W1a, D1, b1a, buf1, buf2, N_NODES);
    hipMemsetAsync(agg, 0, NB * sizeof(unsigned), stream);
    edge_kernel<<<edgeGrid, 256, 0, stream>>>(buf1, buf2, x, psrc, pdst, W1b, W1a + 256 * HID, agg);
    combine_kernel<<<(int)(NB / 256), 256, 0, stream>>>(agg, b1b, buf0, buf0);   // x1 in place

    // ---- layer 2 ----
    hipMemsetAsync(cnt, 0, N_NODES * sizeof(int), stream);
    hist_kernel<<<histGrid, 256, 0, stream>>>(dst2, cnt);
    scan_kernel<<<1, 1024, 0, stream>>>(cnt, cursor);
    scatter_kernel<<<histGrid, 256, 0, stream>>>(src2, dst2, cursor, psrc, pdst);
    mm128_dual_kernel<<<mmGrid, 256, 0, stream>>>(buf0, W2a, D2, b2a, buf1, buf2, N_NODES);
    hipMemsetAsync(agg, 0, NB * sizeof(unsigned), stream);
    edge_kernel<<<edgeGrid, 256, 0, stream>>>(buf1, buf2, x, psrc, pdst, W2b, W2a + 256 * HID, agg);
    combine_kernel<<<(int)(NB / 256), 256, 0, stream>>>(agg, b2b, buf0, buf1);   // x2 -> buf1

    pool_kernel<<<N_GRAPHS, 256, 0, stream>>>(buf0, buf1, batch, pooled);
    final_kernel<<<N_GRAPHS, 128, 0, stream>>>(pooled, Wf1, bf1, Wf2, bf2, (float*)d_out);
}

// Round 5
// 1229.341 us; speedup vs baseline: 3.0305x; 1.4058x over previous
//
#include <hip/hip_runtime.h>
#include <cstdint>

#define N_NODES 100000
#define N_EDGES 500000
#define N_GRAPHS 128
#define HID 128

typedef __attribute__((ext_vector_type(8))) short short8;
typedef __attribute__((ext_vector_type(4))) float f32x4;

// ---- monotone float<->uint encoding for max; enc==0 marks "never written" ----
__device__ __forceinline__ unsigned encf(float f) {
    unsigned u = __float_as_uint(f);
    return (u & 0x80000000u) ? ~u : (u | 0x80000000u);
}
__device__ __forceinline__ float decf(unsigned e) {
    unsigned u = (e & 0x80000000u) ? (e & 0x7FFFFFFFu) : ~e;
    return __uint_as_float(u);
}
// round-to-nearest-even fp32 -> bf16 (finite inputs only)
__device__ __forceinline__ unsigned pk_bf16(float a, float b) {
    unsigned ua = __float_as_uint(a);
    unsigned ub = __float_as_uint(b);
    ua = (ua + 0x7fffu + ((ua >> 16) & 1u)) >> 16;
    ub = (ub + 0x7fffu + ((ub >> 16) & 1u)) & 0xffff0000u;
    return ua | ub;
}
__device__ __forceinline__ ushort bf16r(float f) {
    unsigned u = __float_as_uint(f);
    return (ushort)((u + 0x7fffu + ((u >> 16) & 1u)) >> 16);
}

// ---- prep: fold key-embedding through W0; D = Wa[128:256]-Wa[0:128] ----
__global__ void prep_kernel(const float* __restrict__ W_enc, const float* __restrict__ b_enc,
                            const float* __restrict__ W0, const float* __restrict__ b0,
                            const float* __restrict__ W1a, const float* __restrict__ W2a,
                            float* __restrict__ wkey, float* __restrict__ bias0,
                            float* __restrict__ D1, float* __restrict__ D2) {
    int tid = threadIdx.x;
    if (tid < HID) {
        float wk = 0.f, bk = b0[tid];
        for (int k = 0; k < 32; ++k) {
            float w = W0[(15 + k) * HID + tid];
            wk += W_enc[k] * w;
            bk += b_enc[k] * w;
        }
        wkey[tid] = wk;
        bias0[tid] = bk;
    }
    for (int i = tid; i < HID * HID; i += blockDim.x) {
        D1[i] = W1a[HID * HID + i] - W1a[i];
        D2[i] = W2a[HID * HID + i] - W2a[i];
    }
}

// ---- transpose+convert Wb (fp32 [k][n]) -> WbT (bf16 [n][k]) ----
__global__ __launch_bounds__(256) void transp_kernel(const float* __restrict__ W,
                                                     ushort* __restrict__ WT) {
    int i = blockIdx.x * 256 + threadIdx.x;   // i = n*128 + k
    int n = i >> 7, k = i & 127;
    WT[i] = bf16r(W[k * HID + n]);
}

// ---- encoder: h = relu(features @ W0[0:15] + key*wkey + bias0) ----
__global__ __launch_bounds__(256) void encode_kernel(const float* __restrict__ x,
                                                     const float* __restrict__ W0,
                                                     const float* __restrict__ wkey,
                                                     const float* __restrict__ bias0,
                                                     float* __restrict__ h) {
    int n = blockIdx.x * 2 + (threadIdx.x >> 7);
    int j = threadIdx.x & 127;
    const float* xr = x + n * 16;
    float acc = bias0[j] + xr[0] * wkey[j];
#pragma unroll
    for (int f = 0; f < 15; ++f)
        acc = fmaf(xr[1 + f], W0[f * HID + j], acc);
    h[n * HID + j] = fmaxf(acc, 0.f);
}

// ---- dual (N x 128) @ (128 x 128) -> bf16: out_u = in@Wu ; out_v = in@Wv + bv ----
// 128-row tiles (halved weight re-reads vs 64), bf16 output (halved writes).
__global__ __launch_bounds__(256, 2) void mm128_dual_kernel(const float* __restrict__ in,
                                                            const float* __restrict__ Wu,
                                                            const float* __restrict__ Wv,
                                                            const float* __restrict__ bv,
                                                            ushort* __restrict__ outu,
                                                            ushort* __restrict__ outv, int nrows) {
    __shared__ __align__(16) float sA[128 * 132];    // 67.6 KB -> 2 blocks/CU
    int tid = threadIdx.x;
    int n0 = blockIdx.x * 128;
#pragma unroll
    for (int q = 0; q < 16; ++q) {
        int idx = q * 256 + tid;
        int r = idx >> 5, c4 = idx & 31;
        int n = n0 + r;
        float4 vv = (n < nrows) ? ((const float4*)(in + (size_t)n * HID))[c4]
                                : make_float4(0.f, 0.f, 0.f, 0.f);
        *((float4*)(sA + r * 132 + c4 * 4)) = vv;
    }
    __syncthreads();
    int cg = tid & 15;   // cols cg*8..+7
    int rg = tid >> 4;   // rows rg*8..+7
#pragma unroll
    for (int pass = 0; pass < 2; ++pass) {
        const float* W = pass ? Wv : Wu;
        ushort* out = pass ? outv : outu;
        const float* WC = W + cg * 8;
        float acc[8][8];
#pragma unroll
        for (int r = 0; r < 8; ++r)
#pragma unroll
            for (int q = 0; q < 8; ++q) acc[r][q] = 0.f;
        for (int k4 = 0; k4 < 128; k4 += 4) {
            float4 a[8];
#pragma unroll
            for (int r = 0; r < 8; ++r)
                a[r] = *(const float4*)(sA + (rg * 8 + r) * 132 + k4);
#pragma unroll
            for (int kk = 0; kk < 4; ++kk) {
                const float4* wr = (const float4*)(WC + (k4 + kk) * HID);
                float4 w0 = wr[0], w1 = wr[1];
#pragma unroll
                for (int r = 0; r < 8; ++r) {
                    float av = ((const float*)&a[r])[kk];
                    acc[r][0] = fmaf(av, w0.x, acc[r][0]);
                    acc[r][1] = fmaf(av, w0.y, acc[r][1]);
                    acc[r][2] = fmaf(av, w0.z, acc[r][2]);
                    acc[r][3] = fmaf(av, w0.w, acc[r][3]);
                    acc[r][4] = fmaf(av, w1.x, acc[r][4]);
                    acc[r][5] = fmaf(av, w1.y, acc[r][5]);
                    acc[r][6] = fmaf(av, w1.z, acc[r][6]);
                    acc[r][7] = fmaf(av, w1.w, acc[r][7]);
                }
            }
        }
        float bvv[8];
#pragma unroll
        for (int q = 0; q < 8; ++q) bvv[q] = pass ? bv[cg * 8 + q] : 0.f;
#pragma unroll
        for (int r = 0; r < 8; ++r) {
            int n = n0 + rg * 8 + r;
            if (n < nrows) {
                uint4 o;
                o.x = pk_bf16(acc[r][0] + bvv[0], acc[r][1] + bvv[1]);
                o.y = pk_bf16(acc[r][2] + bvv[2], acc[r][3] + bvv[3]);
                o.z = pk_bf16(acc[r][4] + bvv[4], acc[r][5] + bvv[5]);
                o.w = pk_bf16(acc[r][6] + bvv[6], acc[r][7] + bvv[7]);
                *(uint4*)(out + (size_t)n * HID + cg * 8) = o;
            }
        }
    }
}

// ---- CSR build: histogram -> scan -> scatter (counting sort by dst) ----
__global__ __launch_bounds__(256) void hist_kernel(const int* __restrict__ dst, int* __restrict__ cnt) {
    int e = blockIdx.x * 256 + threadIdx.x;
    if (e < N_EDGES) atomicAdd(&cnt[dst[e]], 1);
}

__global__ __launch_bounds__(1024) void scan_kernel(const int* __restrict__ cnt, int* __restrict__ cursor) {
    __shared__ int part[1024];
    int tid = threadIdx.x;
    const int SPAN = (N_NODES + 1023) / 1024;   // 98
    int base = tid * SPAN;
    int s = 0;
    for (int i = 0; i < SPAN; ++i) {
        int idx = base + i;
        if (idx < N_NODES) s += cnt[idx];
    }
    part[tid] = s;
    __syncthreads();
    for (int off = 1; off < 1024; off <<= 1) {
        int v = (tid >= off) ? part[tid - off] : 0;
        __syncthreads();
        part[tid] += v;
        __syncthreads();
    }
    int run = (tid > 0) ? part[tid - 1] : 0;
    for (int i = 0; i < SPAN; ++i) {
        int idx = base + i;
        if (idx < N_NODES) {
            cursor[idx] = run;
            run += cnt[idx];
        }
    }
}

__global__ __launch_bounds__(256) void scatter_kernel(const int* __restrict__ src,
                                                      const int* __restrict__ dst,
                                                      int* __restrict__ cursor,
                                                      int* __restrict__ psrc,
                                                      int* __restrict__ pdst) {
    int e = blockIdx.x * 256 + threadIdx.x;
    if (e < N_EDGES) {
        int d = dst[e];
        int pos = atomicAdd(&cursor[d], 1);
        psrc[pos] = src[e];
        pdst[pos] = d;
    }
}

// ---- edge conv v5: bf16 MFMA, 64-edge dst-sorted windows ----
// phase1: t = leaky(u[src]+v[dst]+kd*w256) -> LDS bf16 [64][136]
// phase2: msg = t @ Wb via mfma_f32_16x16x32_bf16 (WbT bf16 staged in LDS)
// epilogue: msg -> LDS bf16 transposed [128 cols][68 edges]
// phase3: segmented max over dst runs, boundary runs via atomicMax
__global__ __launch_bounds__(256, 3) void edge_kernel(const ushort* __restrict__ u,
                                                      const ushort* __restrict__ v,
                                                      const float* __restrict__ x,
                                                      const int* __restrict__ psrc,
                                                      const int* __restrict__ pdst,
                                                      const ushort* __restrict__ WbT,
                                                      const float* __restrict__ wlast,
                                                      unsigned* __restrict__ agg) {
    __shared__ ushort sWT[128 * 136];   // 34816 B: WbT[n][k] bf16, padded stride
    __shared__ ushort sU[64 * 136];     // 17408 B union: t[64][136] then msgT[128][68]
    __shared__ int sSrc[64], sDst[64];
    __shared__ float sKd[64];
    __shared__ int sPrev, sNext;
    int tid = threadIdx.x;
    int w0 = blockIdx.x * 64;

    // stage WbT: 128x128 bf16 = 2048 16B-chunks
#pragma unroll
    for (int q = 0; q < 8; ++q) {
        int c = q * 256 + tid;
        int n = c >> 4, off = (c & 15) << 3;
        *(uint4*)(sWT + n * 136 + off) = *(const uint4*)(WbT + n * 128 + off);
    }
    if (tid < 64) {
        int e = w0 + tid;
        if (e >= N_EDGES) e = N_EDGES - 1;   // clamp: idempotent under max
        int s = psrc[e], d = pdst[e];
        sSrc[tid] = s;
        sDst[tid] = d;
        sKd[tid] = x[(size_t)s * 16] - x[(size_t)d * 16];
    }
    if (tid == 64) sPrev = (w0 > 0) ? pdst[w0 - 1] : -1;
    if (tid == 65) sNext = (w0 + 64 < N_EDGES) ? pdst[w0 + 64] : -1;
    __syncthreads();

    // phase 1: 4 threads/edge, 32 cols each
    {
        int eloc = tid >> 2;
        int kb = (tid & 3) << 5;
        int s = sSrc[eloc], d = sDst[eloc];
        float kd = sKd[eloc];
        const uint4* ur = (const uint4*)(u + (size_t)s * HID + kb);
        const uint4* vr = (const uint4*)(v + (size_t)d * HID + kb);
        uint4 uu[4], vv[4];
#pragma unroll
        for (int q = 0; q < 4; ++q) uu[q] = ur[q];
#pragma unroll
        for (int q = 0; q < 4; ++q) vv[q] = vr[q];
        const float4* wr4 = (const float4*)(wlast + kb);
        uint4* tout = (uint4*)(sU + eloc * 136 + kb);
#pragma unroll
        for (int q = 0; q < 4; ++q) {
            float4 wa = wr4[2 * q], wb = wr4[2 * q + 1];
            float w[8] = {wa.x, wa.y, wa.z, wa.w, wb.x, wb.y, wb.z, wb.w};
            unsigned pu[4] = {uu[q].x, uu[q].y, uu[q].z, uu[q].w};
            unsigned pv[4] = {vv[q].x, vv[q].y, vv[q].z, vv[q].w};
            unsigned pk[4];
#pragma unroll
            for (int p = 0; p < 4; ++p) {
                float a0 = __uint_as_float(pu[p] << 16) + __uint_as_float(pv[p] << 16);
                float a1 = __uint_as_float(pu[p] & 0xffff0000u) + __uint_as_float(pv[p] & 0xffff0000u);
                a0 = fmaf(kd, w[2 * p], a0);
                a1 = fmaf(kd, w[2 * p + 1], a1);
                a0 = a0 > 0.f ? a0 : 0.1f * a0;
                a1 = a1 > 0.f ? a1 : 0.1f * a1;
                pk[p] = pk_bf16(a0, a1);
            }
            uint4 o; o.x = pk[0]; o.y = pk[1]; o.z = pk[2]; o.w = pk[3];
            tout[q] = o;
        }
    }
    __syncthreads();

    // phase 2: MFMA. wave wv owns edges wv*16..+15; 8 col-tiles x 4 K-chunks
    int lane = tid & 63, wv = tid >> 6;
    int l15 = lane & 15, quad = lane >> 4;
    short8 afr[4];
    {
        const ushort* ab = sU + (wv * 16 + l15) * 136 + quad * 8;
#pragma unroll
        for (int kc = 0; kc < 4; ++kc)
            afr[kc] = *(const short8*)(ab + kc * 32);
    }
    f32x4 acc[8];
#pragma unroll
    for (int ct = 0; ct < 8; ++ct) {
        f32x4 a = {0.f, 0.f, 0.f, 0.f};
        const ushort* bb = sWT + (ct * 16 + l15) * 136 + quad * 8;
#pragma unroll
        for (int kc = 0; kc < 4; ++kc) {
            short8 bfr = *(const short8*)(bb + kc * 32);
            a = __builtin_amdgcn_mfma_f32_16x16x32_bf16(afr[kc], bfr, a, 0, 0, 0);
        }
        acc[ct] = a;
    }
    __syncthreads();   // all t reads done -> sU reusable

    // epilogue: D[m][n]: n = ct*16+l15, m(edge) = wv*16 + quad*4 + reg
    // msgT[col][edge] bf16, stride 68
#pragma unroll
    for (int ct = 0; ct < 8; ++ct) {
        uint2 pr;
        pr.x = pk_bf16(acc[ct][0], acc[ct][1]);
        pr.y = pk_bf16(acc[ct][2], acc[ct][3]);
        *(uint2*)(sU + (ct * 16 + l15) * 68 + wv * 16 + quad * 4) = pr;
    }
    __syncthreads();

    // phase 3: segmented max, 2 threads/col (half-window each)
    {
        int j = tid & 127;
        int h = tid >> 7;
        int eBeg = h * 32;
        const ushort* mrow = sU + j * 68 + eBeg;
        float vals[32];
#pragma unroll
        for (int q = 0; q < 8; ++q) {
            ushort4 mv = *(const ushort4*)(mrow + q * 4);
            vals[q * 4 + 0] = __uint_as_float((unsigned)mv.x << 16);
            vals[q * 4 + 1] = __uint_as_float((unsigned)mv.y << 16);
            vals[q * 4 + 2] = __uint_as_float((unsigned)mv.z << 16);
            vals[q * 4 + 3] = __uint_as_float((unsigned)mv.w << 16);
        }
        int prevD = (h == 0) ? sPrev : sDst[31];
        int nextD = (h == 0) ? sDst[32] : sNext;
        int cur = sDst[eBeg], rs = eBeg;
        float mx = vals[0];
        for (int e2 = 1; e2 < 32; ++e2) {
            int d = sDst[eBeg + e2];      // uniform across the half's lanes
            float vv2 = vals[e2];
            if (d != cur) {
                unsigned en = encf(mx);
                unsigned* ap = agg + (size_t)cur * HID + j;
                if (rs == eBeg && cur == prevD) atomicMax(ap, en);
                else *ap = en;
                cur = d; rs = eBeg + e2; mx = vv2;
            } else {
                mx = fmaxf(mx, vv2);
            }
        }
        unsigned en = encf(mx);
        unsigned* ap = agg + (size_t)cur * HID + j;
        if ((rs == eBeg && cur == prevD) || cur == nextD) atomicMax(ap, en);
        else *ap = en;
    }
}

// ---- combine: out = relu((agg? dec(agg)+bb : 0) + base) ----
__global__ __launch_bounds__(256) void combine_kernel(const unsigned* __restrict__ agg,
                                                      const float* __restrict__ bb,
                                                      const float* __restrict__ base,
                                                      float* __restrict__ out) {
    size_t i = (size_t)blockIdx.x * 256 + threadIdx.x;
    unsigned e = agg[i];
    int j = (int)(i & 127);
    float val = (e == 0u) ? 0.f : (decf(e) + bb[j]);
    out[i] = fmaxf(val + base[i], 0.f);
}

// ---- pooling v2: 8 slices per graph, atomic finalize ----
// pooled[g][0..255] = encoded max (unsigned view), [256..511] = float sums
__global__ __launch_bounds__(256) void pool_kernel(const float* __restrict__ x1,
                                                   const float* __restrict__ x2,
                                                   const int* __restrict__ batch,
                                                   float* __restrict__ pooled) {
    int g = blockIdx.x >> 3, s = blockIdx.x & 7;
    int tid = threadIdx.x;
    int lo = 0, hi = N_NODES;
    while (lo < hi) { int mid = (lo + hi) >> 1; if (batch[mid] < g) lo = mid + 1; else hi = mid; }
    int start = lo;
    hi = N_NODES;
    while (lo < hi) { int mid = (lo + hi) >> 1; if (batch[mid] < g + 1) lo = mid + 1; else hi = mid; }
    int end = lo;
    int cnt = end - start;
    int b0 = start + (int)((long long)cnt * s / 8);
    int b1 = start + (int)((long long)cnt * (s + 1) / 8);
    if (b1 <= b0) return;
    const float* srcp = (tid < 128) ? (x1 + tid) : (x2 + (tid - 128));
    float mx = -INFINITY, sm = 0.f;
    for (int n = b0; n < b1; ++n) {
        float vv = srcp[(size_t)n * HID];
        mx = fmaxf(mx, vv);
        sm += vv;
    }
    atomicMax((unsigned*)pooled + (size_t)g * 512 + tid, encf(mx));
    atomicAdd(pooled + (size_t)g * 512 + 256 + tid, sm);
}

// ---- final MLP + log_softmax ----
__global__ __launch_bounds__(128) void final_kernel(const float* __restrict__ pooled,
                                                    const int* __restrict__ batch,
                                                    const float* __restrict__ Wf1,
                                                    const float* __restrict__ bf1,
                                                    const float* __restrict__ Wf2,
                                                    const float* __restrict__ bf2,
                                                    float* __restrict__ out) {
    __shared__ float sP[512];
    __shared__ float sH[128];
    int g = blockIdx.x, tid = threadIdx.x;
    int lo = 0, hi = N_NODES;
    while (lo < hi) { int mid = (lo + hi) >> 1; if (batch[mid] < g) lo = mid + 1; else hi = mid; }
    int start = lo;
    hi = N_NODES;
    while (lo < hi) { int mid = (lo + hi) >> 1; if (batch[mid] < g + 1) lo = mid + 1; else hi = mid; }
    int cnt = lo - start;
    float inv = 1.f / (float)(cnt > 1 ? cnt : 1);
#pragma unroll
    for (int q = 0; q < 4; ++q) {
        int idx = q * 128 + tid;
        float raw;
        if (idx < 256) {
            unsigned e = ((const unsigned*)pooled)[(size_t)g * 512 + idx];
            raw = (e == 0u) ? 0.f : decf(e);
        } else {
            raw = pooled[(size_t)g * 512 + idx] * inv;
        }
        sP[idx] = raw;
    }
    __syncthreads();
    float acc = bf1[tid];
    for (int k = 0; k < 512; ++k) acc = fmaf(sP[k], Wf1[k * HID + tid], acc);
    sH[tid] = fmaxf(acc, 0.f);
    __syncthreads();
    if (tid < 2) {
        float l = bf2[tid];
        for (int k = 0; k < 128; ++k) l = fmaf(sH[k], Wf2[k * 2 + tid], l);
        sP[tid] = l;
    }
    __syncthreads();
    if (tid == 0) {
        float l0 = sP[0], l1 = sP[1];
        float m = fmaxf(l0, l1);
        float ls = m + logf(expf(l0 - m) + expf(l1 - m));
        out[g * 2 + 0] = l0 - ls;
        out[g * 2 + 1] = l1 - ls;
    }
}

extern "C" void kernel_launch(void* const* d_in, const int* in_sizes, int n_in,
                              void* d_out, int out_size, void* d_ws, size_t ws_size,
                              hipStream_t stream) {
    const float* x     = (const float*)d_in[0];
    const float* W_enc = (const float*)d_in[1];
    const float* b_enc = (const float*)d_in[2];
    const float* W0    = (const float*)d_in[3];
    const float* b0    = (const float*)d_in[4];
    const float* W1a   = (const float*)d_in[5];
    const float* b1a   = (const float*)d_in[6];
    const float* W1b   = (const float*)d_in[7];
    const float* b1b   = (const float*)d_in[8];
    const float* W2a   = (const float*)d_in[9];
    const float* b2a   = (const float*)d_in[10];
    const float* W2b   = (const float*)d_in[11];
    const float* b2b   = (const float*)d_in[12];
    const float* Wf1   = (const float*)d_in[13];
    const float* bf1   = (const float*)d_in[14];
    const float* Wf2   = (const float*)d_in[15];
    const float* bf2   = (const float*)d_in[16];
    const int* src1    = (const int*)d_in[17];
    const int* dst1    = (const int*)d_in[18];
    const int* src2    = (const int*)d_in[19];
    const int* dst2    = (const int*)d_in[20];
    const int* batch   = (const int*)d_in[21];

    const size_t NB = (size_t)N_NODES * HID;     // 12.8M elements
    float* buf0  = (float*)d_ws;                 // h -> x1 (in place)
    float* bufx2 = buf0 + NB;                    // x2
    unsigned* agg = (unsigned*)(bufx2 + NB);     // encoded segment-max
    ushort* ubuf = (ushort*)(agg + NB);          // u bf16
    ushort* vbuf = ubuf + NB;                    // v bf16
    ushort* WbT1 = vbuf + NB;                    // 16384
    ushort* WbT2 = WbT1 + HID * HID;             // 16384
    float* wkey  = (float*)(WbT2 + HID * HID);
    float* bias0 = wkey + 128;
    float* D1    = bias0 + 128;
    float* D2    = D1 + HID * HID;
    float* pooled = D2 + HID * HID;              // 128*512 fp32
    int* cnt    = (int*)(pooled + 128 * 512);    // 100000
    int* cursor = cnt + N_NODES;                 // 100000
    int* psrc   = cursor + N_NODES;              // 500000
    int* pdst   = psrc + N_EDGES;                // 500000

    const int histGrid = (N_EDGES + 255) / 256;
    const int edgeGrid = (N_EDGES + 63) / 64;    // 7813 windows of 64
    const int mmGrid   = (N_NODES + 127) / 128;  // 782

    prep_kernel<<<1, 256, 0, stream>>>(W_enc, b_enc, W0, b0, W1a, W2a, wkey, bias0, D1, D2);
    transp_kernel<<<64, 256, 0, stream>>>(W1b, WbT1);
    transp_kernel<<<64, 256, 0, stream>>>(W2b, WbT2);
    encode_kernel<<<N_NODES / 2, 256, 0, stream>>>(x, W0, wkey, bias0, buf0);

    // ---- layer 1 ----
    hipMemsetAsync(cnt, 0, N_NODES * sizeof(int), stream);
    hist_kernel<<<histGrid, 256, 0, stream>>>(dst1, cnt);
    scan_kernel<<<1, 1024, 0, stream>>>(cnt, cursor);
    scatter_kernel<<<histGrid, 256, 0, stream>>>(src1, dst1, cursor, psrc, pdst);
    mm128_dual_kernel<<<mmGrid, 256, 0, stream>>>(buf0, W1a, D1, b1a, ubuf, vbuf, N_NODES);
    hipMemsetAsync(agg, 0, NB * sizeof(unsigned), stream);
    edge_kernel<<<edgeGrid, 256, 0, stream>>>(ubuf, vbuf, x, psrc, pdst, WbT1, W1a + 256 * HID, agg);
    combine_kernel<<<(int)(NB / 256), 256, 0, stream>>>(agg, b1b, buf0, buf0);   // x1 in place

    // ---- layer 2 ----
    hipMemsetAsync(cnt, 0, N_NODES * sizeof(int), stream);
    hist_kernel<<<histGrid, 256, 0, stream>>>(dst2, cnt);
    scan_kernel<<<1, 1024, 0, stream>>>(cnt, cursor);
    scatter_kernel<<<histGrid, 256, 0, stream>>>(src2, dst2, cursor, psrc, pdst);
    mm128_dual_kernel<<<mmGrid, 256, 0, stream>>>(buf0, W2a, D2, b2a, ubuf, vbuf, N_NODES);
    hipMemsetAsync(agg, 0, NB * sizeof(unsigned), stream);
    edge_kernel<<<edgeGrid, 256, 0, stream>>>(ubuf, vbuf, x, psrc, pdst, WbT2, W2a + 256 * HID, agg);
    combine_kernel<<<(int)(NB / 256), 256, 0, stream>>>(agg, b2b, buf0, bufx2); // x2

    hipMemsetAsync(pooled, 0, 128 * 512 * sizeof(float), stream);
    pool_kernel<<<N_GRAPHS * 8, 256, 0, stream>>>(buf0, bufx2, batch, pooled);
    final_kernel<<<N_GRAPHS, 128, 0, stream>>>(pooled, batch, Wf1, bf1, Wf2, bf2, (float*)d_out);
}

// Round 6
// 840.619 us; speedup vs baseline: 4.4319x; 1.4624x over previous
//
#include <hip/hip_runtime.h>
#include <cstdint>

#define N_NODES 100000
#define N_EDGES 500000
#define N_GRAPHS 128
#define HID 128
#define SCAN_B ((N_NODES + 255) / 256)   // 391

typedef __attribute__((ext_vector_type(8))) short short8;
typedef __attribute__((ext_vector_type(4))) float f32x4;

// ---- monotone float<->uint encoding for max; enc==0 marks "never written" ----
__device__ __forceinline__ unsigned encf(float f) {
    unsigned u = __float_as_uint(f);
    return (u & 0x80000000u) ? ~u : (u | 0x80000000u);
}
__device__ __forceinline__ float decf(unsigned e) {
    unsigned u = (e & 0x80000000u) ? (e & 0x7FFFFFFFu) : ~e;
    return __uint_as_float(u);
}
// round-to-nearest-even fp32 -> bf16 (finite inputs only)
__device__ __forceinline__ unsigned pk_bf16(float a, float b) {
    unsigned ua = __float_as_uint(a);
    unsigned ub = __float_as_uint(b);
    ua = (ua + 0x7fffu + ((ua >> 16) & 1u)) >> 16;
    ub = (ub + 0x7fffu + ((ub >> 16) & 1u)) & 0xffff0000u;
    return ua | ub;
}
__device__ __forceinline__ ushort bf16r(float f) {
    unsigned u = __float_as_uint(f);
    return (ushort)((u + 0x7fffu + ((u >> 16) & 1u)) >> 16);
}

// ---- prep: fold key-embedding through W0; D = Wa[128:256]-Wa[0:128] ----
__global__ void prep_kernel(const float* __restrict__ W_enc, const float* __restrict__ b_enc,
                            const float* __restrict__ W0, const float* __restrict__ b0,
                            const float* __restrict__ W1a, const float* __restrict__ W2a,
                            float* __restrict__ wkey, float* __restrict__ bias0,
                            float* __restrict__ D1, float* __restrict__ D2) {
    int tid = threadIdx.x;
    if (tid < HID) {
        float wk = 0.f, bk = b0[tid];
        for (int k = 0; k < 32; ++k) {
            float w = W0[(15 + k) * HID + tid];
            wk += W_enc[k] * w;
            bk += b_enc[k] * w;
        }
        wkey[tid] = wk;
        bias0[tid] = bk;
    }
    for (int i = tid; i < HID * HID; i += blockDim.x) {
        D1[i] = W1a[HID * HID + i] - W1a[i];
        D2[i] = W2a[HID * HID + i] - W2a[i];
    }
}

// ---- transpose+convert Wb (fp32 [k][n]) -> WbT (bf16 [n][k]) ----
__global__ __launch_bounds__(256) void transp_kernel(const float* __restrict__ W,
                                                     ushort* __restrict__ WT) {
    int i = blockIdx.x * 256 + threadIdx.x;   // i = n*128 + k
    int n = i >> 7, k = i & 127;
    WT[i] = bf16r(W[k * HID + n]);
}

// ---- encoder: h = relu(features @ W0[0:15] + key*wkey + bias0) ----
__global__ __launch_bounds__(256) void encode_kernel(const float* __restrict__ x,
                                                     const float* __restrict__ W0,
                                                     const float* __restrict__ wkey,
                                                     const float* __restrict__ bias0,
                                                     float* __restrict__ h) {
    int n = blockIdx.x * 2 + (threadIdx.x >> 7);
    int j = threadIdx.x & 127;
    const float* xr = x + n * 16;
    float acc = bias0[j] + xr[0] * wkey[j];
#pragma unroll
    for (int f = 0; f < 15; ++f)
        acc = fmaf(xr[1 + f], W0[f * HID + j], acc);
    h[n * HID + j] = fmaxf(acc, 0.f);
}

// ---- dual (N x 128) @ (128 x 128) -> bf16: out_u = in@Wu ; out_v = in@Wv + bv ----
__global__ __launch_bounds__(256, 2) void mm128_dual_kernel(const float* __restrict__ in,
                                                            const float* __restrict__ Wu,
                                                            const float* __restrict__ Wv,
                                                            const float* __restrict__ bv,
                                                            ushort* __restrict__ outu,
                                                            ushort* __restrict__ outv, int nrows) {
    __shared__ __align__(16) float sA[128 * 132];    // 67.6 KB -> 2 blocks/CU
    int tid = threadIdx.x;
    int n0 = blockIdx.x * 128;
#pragma unroll
    for (int q = 0; q < 16; ++q) {
        int idx = q * 256 + tid;
        int r = idx >> 5, c4 = idx & 31;
        int n = n0 + r;
        float4 vv = (n < nrows) ? ((const float4*)(in + (size_t)n * HID))[c4]
                                : make_float4(0.f, 0.f, 0.f, 0.f);
        *((float4*)(sA + r * 132 + c4 * 4)) = vv;
    }
    __syncthreads();
    int cg = tid & 15;   // cols cg*8..+7
    int rg = tid >> 4;   // rows rg*8..+7
#pragma unroll
    for (int pass = 0; pass < 2; ++pass) {
        const float* W = pass ? Wv : Wu;
        ushort* out = pass ? outv : outu;
        const float* WC = W + cg * 8;
        float acc[8][8];
#pragma unroll
        for (int r = 0; r < 8; ++r)
#pragma unroll
            for (int q = 0; q < 8; ++q) acc[r][q] = 0.f;
        for (int k4 = 0; k4 < 128; k4 += 4) {
            float4 a[8];
#pragma unroll
            for (int r = 0; r < 8; ++r)
                a[r] = *(const float4*)(sA + (rg * 8 + r) * 132 + k4);
#pragma unroll
            for (int kk = 0; kk < 4; ++kk) {
                const float4* wr = (const float4*)(WC + (k4 + kk) * HID);
                float4 w0 = wr[0], w1 = wr[1];
#pragma unroll
                for (int r = 0; r < 8; ++r) {
                    float av = ((const float*)&a[r])[kk];
                    acc[r][0] = fmaf(av, w0.x, acc[r][0]);
                    acc[r][1] = fmaf(av, w0.y, acc[r][1]);
                    acc[r][2] = fmaf(av, w0.z, acc[r][2]);
                    acc[r][3] = fmaf(av, w0.w, acc[r][3]);
                    acc[r][4] = fmaf(av, w1.x, acc[r][4]);
                    acc[r][5] = fmaf(av, w1.y, acc[r][5]);
                    acc[r][6] = fmaf(av, w1.z, acc[r][6]);
                    acc[r][7] = fmaf(av, w1.w, acc[r][7]);
                }
            }
        }
        float bvv[8];
#pragma unroll
        for (int q = 0; q < 8; ++q) bvv[q] = pass ? bv[cg * 8 + q] : 0.f;
#pragma unroll
        for (int r = 0; r < 8; ++r) {
            int n = n0 + rg * 8 + r;
            if (n < nrows) {
                uint4 o;
                o.x = pk_bf16(acc[r][0] + bvv[0], acc[r][1] + bvv[1]);
                o.y = pk_bf16(acc[r][2] + bvv[2], acc[r][3] + bvv[3]);
                o.z = pk_bf16(acc[r][4] + bvv[4], acc[r][5] + bvv[5]);
                o.w = pk_bf16(acc[r][6] + bvv[6], acc[r][7] + bvv[7]);
                *(uint4*)(out + (size_t)n * HID + cg * 8) = o;
            }
        }
    }
}

// ---- CSR build: histogram -> hierarchical scan -> scatter ----
__global__ __launch_bounds__(256) void hist_kernel(const int* __restrict__ dst, int* __restrict__ cnt) {
    int e = blockIdx.x * 256 + threadIdx.x;
    if (e < N_EDGES) atomicAdd(&cnt[dst[e]], 1);
}

// scan1: per-block inclusive scan -> exclusive prefixes + block totals
__global__ __launch_bounds__(256) void scan1_kernel(const int* __restrict__ cnt,
                                                    int* __restrict__ cursor,
                                                    int* __restrict__ partials) {
    __shared__ int tmp[256];
    int tid = threadIdx.x;
    int gid = blockIdx.x * 256 + tid;
    int v = (gid < N_NODES) ? cnt[gid] : 0;
    tmp[tid] = v;
    __syncthreads();
#pragma unroll
    for (int off = 1; off < 256; off <<= 1) {
        int t = (tid >= off) ? tmp[tid - off] : 0;
        __syncthreads();
        tmp[tid] += t;
        __syncthreads();
    }
    if (gid < N_NODES) cursor[gid] = tmp[tid] - v;   // exclusive
    if (tid == 255) partials[blockIdx.x] = tmp[255];
}

// scan2: single small block scans the 391 partials (exclusive, in place)
__global__ __launch_bounds__(512) void scan2_kernel(int* __restrict__ partials) {
    __shared__ int tmp[512];
    int tid = threadIdx.x;
    int v = (tid < SCAN_B) ? partials[tid] : 0;
    tmp[tid] = v;
    __syncthreads();
#pragma unroll
    for (int off = 1; off < 512; off <<= 1) {
        int t = (tid >= off) ? tmp[tid - off] : 0;
        __syncthreads();
        tmp[tid] += t;
        __syncthreads();
    }
    if (tid < SCAN_B) partials[tid] = tmp[tid] - v;  // exclusive
}

// scan3: add block offsets
__global__ __launch_bounds__(256) void scan3_kernel(int* __restrict__ cursor,
                                                    const int* __restrict__ partials) {
    int gid = blockIdx.x * 256 + threadIdx.x;
    if (gid < N_NODES) cursor[gid] += partials[blockIdx.x];
}

__global__ __launch_bounds__(256) void scatter_kernel(const int* __restrict__ src,
                                                      const int* __restrict__ dst,
                                                      int* __restrict__ cursor,
                                                      int* __restrict__ psrc,
                                                      int* __restrict__ pdst) {
    int e = blockIdx.x * 256 + threadIdx.x;
    if (e < N_EDGES) {
        int d = dst[e];
        int pos = atomicAdd(&cursor[d], 1);
        psrc[pos] = src[e];
        pdst[pos] = d;
    }
}

// ---- edge conv v5: bf16 MFMA, 64-edge dst-sorted windows ----
__global__ __launch_bounds__(256, 3) void edge_kernel(const ushort* __restrict__ u,
                                                      const ushort* __restrict__ v,
                                                      const float* __restrict__ x,
                                                      const int* __restrict__ psrc,
                                                      const int* __restrict__ pdst,
                                                      const ushort* __restrict__ WbT,
                                                      const float* __restrict__ wlast,
                                                      unsigned* __restrict__ agg) {
    __shared__ ushort sWT[128 * 136];   // 34816 B: WbT[n][k] bf16, padded stride
    __shared__ ushort sU[64 * 136];     // 17408 B union: t[64][136] then msgT[128][68]
    __shared__ int sSrc[64], sDst[64];
    __shared__ float sKd[64];
    __shared__ int sPrev, sNext;
    int tid = threadIdx.x;
    int w0 = blockIdx.x * 64;

#pragma unroll
    for (int q = 0; q < 8; ++q) {
        int c = q * 256 + tid;
        int n = c >> 4, off = (c & 15) << 3;
        *(uint4*)(sWT + n * 136 + off) = *(const uint4*)(WbT + n * 128 + off);
    }
    if (tid < 64) {
        int e = w0 + tid;
        if (e >= N_EDGES) e = N_EDGES - 1;   // clamp: idempotent under max
        int s = psrc[e], d = pdst[e];
        sSrc[tid] = s;
        sDst[tid] = d;
        sKd[tid] = x[(size_t)s * 16] - x[(size_t)d * 16];
    }
    if (tid == 64) sPrev = (w0 > 0) ? pdst[w0 - 1] : -1;
    if (tid == 65) sNext = (w0 + 64 < N_EDGES) ? pdst[w0 + 64] : -1;
    __syncthreads();

    // phase 1: 4 threads/edge, 32 cols each
    {
        int eloc = tid >> 2;
        int kb = (tid & 3) << 5;
        int s = sSrc[eloc], d = sDst[eloc];
        float kd = sKd[eloc];
        const uint4* ur = (const uint4*)(u + (size_t)s * HID + kb);
        const uint4* vr = (const uint4*)(v + (size_t)d * HID + kb);
        uint4 uu[4], vv[4];
#pragma unroll
        for (int q = 0; q < 4; ++q) uu[q] = ur[q];
#pragma unroll
        for (int q = 0; q < 4; ++q) vv[q] = vr[q];
        const float4* wr4 = (const float4*)(wlast + kb);
        uint4* tout = (uint4*)(sU + eloc * 136 + kb);
#pragma unroll
        for (int q = 0; q < 4; ++q) {
            float4 wa = wr4[2 * q], wb = wr4[2 * q + 1];
            float w[8] = {wa.x, wa.y, wa.z, wa.w, wb.x, wb.y, wb.z, wb.w};
            unsigned pu[4] = {uu[q].x, uu[q].y, uu[q].z, uu[q].w};
            unsigned pv[4] = {vv[q].x, vv[q].y, vv[q].z, vv[q].w};
            unsigned pk[4];
#pragma unroll
            for (int p = 0; p < 4; ++p) {
                float a0 = __uint_as_float(pu[p] << 16) + __uint_as_float(pv[p] << 16);
                float a1 = __uint_as_float(pu[p] & 0xffff0000u) + __uint_as_float(pv[p] & 0xffff0000u);
                a0 = fmaf(kd, w[2 * p], a0);
                a1 = fmaf(kd, w[2 * p + 1], a1);
                a0 = a0 > 0.f ? a0 : 0.1f * a0;
                a1 = a1 > 0.f ? a1 : 0.1f * a1;
                pk[p] = pk_bf16(a0, a1);
            }
            uint4 o; o.x = pk[0]; o.y = pk[1]; o.z = pk[2]; o.w = pk[3];
            tout[q] = o;
        }
    }
    __syncthreads();

    // phase 2: MFMA. wave wv owns edges wv*16..+15; 8 col-tiles x 4 K-chunks
    int lane = tid & 63, wv = tid >> 6;
    int l15 = lane & 15, quad = lane >> 4;
    short8 afr[4];
    {
        const ushort* ab = sU + (wv * 16 + l15) * 136 + quad * 8;
#pragma unroll
        for (int kc = 0; kc < 4; ++kc)
            afr[kc] = *(const short8*)(ab + kc * 32);
    }
    f32x4 acc[8];
#pragma unroll
    for (int ct = 0; ct < 8; ++ct) {
        f32x4 a = {0.f, 0.f, 0.f, 0.f};
        const ushort* bb = sWT + (ct * 16 + l15) * 136 + quad * 8;
#pragma unroll
        for (int kc = 0; kc < 4; ++kc) {
            short8 bfr = *(const short8*)(bb + kc * 32);
            a = __builtin_amdgcn_mfma_f32_16x16x32_bf16(afr[kc], bfr, a, 0, 0, 0);
        }
        acc[ct] = a;
    }
    __syncthreads();   // all t reads done -> sU reusable

    // epilogue: msgT[col][edge] bf16, stride 68
#pragma unroll
    for (int ct = 0; ct < 8; ++ct) {
        uint2 pr;
        pr.x = pk_bf16(acc[ct][0], acc[ct][1]);
        pr.y = pk_bf16(acc[ct][2], acc[ct][3]);
        *(uint2*)(sU + (ct * 16 + l15) * 68 + wv * 16 + quad * 4) = pr;
    }
    __syncthreads();

    // phase 3: segmented max, 2 threads/col (half-window each)
    {
        int j = tid & 127;
        int h = tid >> 7;
        int eBeg = h * 32;
        const ushort* mrow = sU + j * 68 + eBeg;
        float vals[32];
#pragma unroll
        for (int q = 0; q < 8; ++q) {
            ushort4 mv = *(const ushort4*)(mrow + q * 4);
            vals[q * 4 + 0] = __uint_as_float((unsigned)mv.x << 16);
            vals[q * 4 + 1] = __uint_as_float((unsigned)mv.y << 16);
            vals[q * 4 + 2] = __uint_as_float((unsigned)mv.z << 16);
            vals[q * 4 + 3] = __uint_as_float((unsigned)mv.w << 16);
        }
        int prevD = (h == 0) ? sPrev : sDst[31];
        int nextD = (h == 0) ? sDst[32] : sNext;
        int cur = sDst[eBeg], rs = eBeg;
        float mx = vals[0];
        for (int e2 = 1; e2 < 32; ++e2) {
            int d = sDst[eBeg + e2];      // uniform across the half's lanes
            float vv2 = vals[e2];
            if (d != cur) {
                unsigned en = encf(mx);
                unsigned* ap = agg + (size_t)cur * HID + j;
                if (rs == eBeg && cur == prevD) atomicMax(ap, en);
                else *ap = en;
                cur = d; rs = eBeg + e2; mx = vv2;
            } else {
                mx = fmaxf(mx, vv2);
            }
        }
        unsigned en = encf(mx);
        unsigned* ap = agg + (size_t)cur * HID + j;
        if ((rs == eBeg && cur == prevD) || cur == nextD) atomicMax(ap, en);
        else *ap = en;
    }
}

// ---- combine: out = relu((agg? dec(agg)+bb : 0) + base) ----
__global__ __launch_bounds__(256) void combine_kernel(const unsigned* __restrict__ agg,
                                                      const float* __restrict__ bb,
                                                      const float* __restrict__ base,
                                                      float* __restrict__ out) {
    size_t i = (size_t)blockIdx.x * 256 + threadIdx.x;
    unsigned e = agg[i];
    int j = (int)(i & 127);
    float val = (e == 0u) ? 0.f : (decf(e) + bb[j]);
    out[i] = fmaxf(val + base[i], 0.f);
}

// ---- pooling: 8 slices per graph, atomic finalize ----
__global__ __launch_bounds__(256) void pool_kernel(const float* __restrict__ x1,
                                                   const float* __restrict__ x2,
                                                   const int* __restrict__ batch,
                                                   float* __restrict__ pooled) {
    int g = blockIdx.x >> 3, s = blockIdx.x & 7;
    int tid = threadIdx.x;
    int lo = 0, hi = N_NODES;
    while (lo < hi) { int mid = (lo + hi) >> 1; if (batch[mid] < g) lo = mid + 1; else hi = mid; }
    int start = lo;
    hi = N_NODES;
    while (lo < hi) { int mid = (lo + hi) >> 1; if (batch[mid] < g + 1) lo = mid + 1; else hi = mid; }
    int end = lo;
    int cnt = end - start;
    int b0 = start + (int)((long long)cnt * s / 8);
    int b1 = start + (int)((long long)cnt * (s + 1) / 8);
    if (b1 <= b0) return;
    const float* srcp = (tid < 128) ? (x1 + tid) : (x2 + (tid - 128));
    float mx = -INFINITY, sm = 0.f;
    for (int n = b0; n < b1; ++n) {
        float vv = srcp[(size_t)n * HID];
        mx = fmaxf(mx, vv);
        sm += vv;
    }
    atomicMax((unsigned*)pooled + (size_t)g * 512 + tid, encf(mx));
    atomicAdd(pooled + (size_t)g * 512 + 256 + tid, sm);
}

// ---- final MLP + log_softmax ----
__global__ __launch_bounds__(128) void final_kernel(const float* __restrict__ pooled,
                                                    const int* __restrict__ batch,
                                                    const float* __restrict__ Wf1,
                                                    const float* __restrict__ bf1,
                                                    const float* __restrict__ Wf2,
                                                    const float* __restrict__ bf2,
                                                    float* __restrict__ out) {
    __shared__ float sP[512];
    __shared__ float sH[128];
    int g = blockIdx.x, tid = threadIdx.x;
    int lo = 0, hi = N_NODES;
    while (lo < hi) { int mid = (lo + hi) >> 1; if (batch[mid] < g) lo = mid + 1; else hi = mid; }
    int start = lo;
    hi = N_NODES;
    while (lo < hi) { int mid = (lo + hi) >> 1; if (batch[mid] < g + 1) lo = mid + 1; else hi = mid; }
    int cnt = lo - start;
    float inv = 1.f / (float)(cnt > 1 ? cnt : 1);
#pragma unroll
    for (int q = 0; q < 4; ++q) {
        int idx = q * 128 + tid;
        float raw;
        if (idx < 256) {
            unsigned e = ((const unsigned*)pooled)[(size_t)g * 512 + idx];
            raw = (e == 0u) ? 0.f : decf(e);
        } else {
            raw = pooled[(size_t)g * 512 + idx] * inv;
        }
        sP[idx] = raw;
    }
    __syncthreads();
    float acc = bf1[tid];
    for (int k = 0; k < 512; ++k) acc = fmaf(sP[k], Wf1[k * HID + tid], acc);
    sH[tid] = fmaxf(acc, 0.f);
    __syncthreads();
    if (tid < 2) {
        float l = bf2[tid];
        for (int k = 0; k < 128; ++k) l = fmaf(sH[k], Wf2[k * 2 + tid], l);
        sP[tid] = l;
    }
    __syncthreads();
    if (tid == 0) {
        float l0 = sP[0], l1 = sP[1];
        float m = fmaxf(l0, l1);
        float ls = m + logf(expf(l0 - m) + expf(l1 - m));
        out[g * 2 + 0] = l0 - ls;
        out[g * 2 + 1] = l1 - ls;
    }
}

extern "C" void kernel_launch(void* const* d_in, const int* in_sizes, int n_in,
                              void* d_out, int out_size, void* d_ws, size_t ws_size,
                              hipStream_t stream) {
    const float* x     = (const float*)d_in[0];
    const float* W_enc = (const float*)d_in[1];
    const float* b_enc = (const float*)d_in[2];
    const float* W0    = (const float*)d_in[3];
    const float* b0    = (const float*)d_in[4];
    const float* W1a   = (const float*)d_in[5];
    const float* b1a   = (const float*)d_in[6];
    const float* W1b   = (const float*)d_in[7];
    const float* b1b   = (const float*)d_in[8];
    const float* W2a   = (const float*)d_in[9];
    const float* b2a   = (const float*)d_in[10];
    const float* W2b   = (const float*)d_in[11];
    const float* b2b   = (const float*)d_in[12];
    const float* Wf1   = (const float*)d_in[13];
    const float* bf1   = (const float*)d_in[14];
    const float* Wf2   = (const float*)d_in[15];
    const float* bf2   = (const float*)d_in[16];
    const int* src1    = (const int*)d_in[17];
    const int* dst1    = (const int*)d_in[18];
    const int* src2    = (const int*)d_in[19];
    const int* dst2    = (const int*)d_in[20];
    const int* batch   = (const int*)d_in[21];

    const size_t NB = (size_t)N_NODES * HID;     // 12.8M elements
    float* buf0  = (float*)d_ws;                 // h -> x1 (in place)
    float* bufx2 = buf0 + NB;                    // x2
    unsigned* agg = (unsigned*)(bufx2 + NB);     // encoded segment-max
    ushort* ubuf = (ushort*)(agg + NB);          // u bf16
    ushort* vbuf = ubuf + NB;                    // v bf16
    ushort* WbT1 = vbuf + NB;                    // 16384
    ushort* WbT2 = WbT1 + HID * HID;             // 16384
    float* wkey  = (float*)(WbT2 + HID * HID);
    float* bias0 = wkey + 128;
    float* D1    = bias0 + 128;
    float* D2    = D1 + HID * HID;
    float* pooled = D2 + HID * HID;              // 128*512 fp32
    int* cnt    = (int*)(pooled + 128 * 512);    // 100000
    int* cursor = cnt + N_NODES;                 // 100000
    int* partials = cursor + N_NODES;            // SCAN_B
    int* psrc   = partials + 512;                // 500000
    int* pdst   = psrc + N_EDGES;                // 500000

    const int histGrid = (N_EDGES + 255) / 256;
    const int edgeGrid = (N_EDGES + 63) / 64;    // 7813 windows of 64
    const int mmGrid   = (N_NODES + 127) / 128;  // 782

    prep_kernel<<<1, 256, 0, stream>>>(W_enc, b_enc, W0, b0, W1a, W2a, wkey, bias0, D1, D2);
    transp_kernel<<<64, 256, 0, stream>>>(W1b, WbT1);
    transp_kernel<<<64, 256, 0, stream>>>(W2b, WbT2);
    encode_kernel<<<N_NODES / 2, 256, 0, stream>>>(x, W0, wkey, bias0, buf0);

    // ---- layer 1 ----
    hipMemsetAsync(cnt, 0, N_NODES * sizeof(int), stream);
    hist_kernel<<<histGrid, 256, 0, stream>>>(dst1, cnt);
    scan1_kernel<<<SCAN_B, 256, 0, stream>>>(cnt, cursor, partials);
    scan2_kernel<<<1, 512, 0, stream>>>(partials);
    scan3_kernel<<<SCAN_B, 256, 0, stream>>>(cursor, partials);
    scatter_kernel<<<histGrid, 256, 0, stream>>>(src1, dst1, cursor, psrc, pdst);
    mm128_dual_kernel<<<mmGrid, 256, 0, stream>>>(buf0, W1a, D1, b1a, ubuf, vbuf, N_NODES);
    hipMemsetAsync(agg, 0, NB * sizeof(unsigned), stream);
    edge_kernel<<<edgeGrid, 256, 0, stream>>>(ubuf, vbuf, x, psrc, pdst, WbT1, W1a + 256 * HID, agg);
    combine_kernel<<<(int)(NB / 256), 256, 0, stream>>>(agg, b1b, buf0, buf0);   // x1 in place

    // ---- layer 2 ----
    hipMemsetAsync(cnt, 0, N_NODES * sizeof(int), stream);
    hist_kernel<<<histGrid, 256, 0, stream>>>(dst2, cnt);
    scan1_kernel<<<SCAN_B, 256, 0, stream>>>(cnt, cursor, partials);
    scan2_kernel<<<1, 512, 0, stream>>>(partials);
    scan3_kernel<<<SCAN_B, 256, 0, stream>>>(cursor, partials);
    scatter_kernel<<<histGrid, 256, 0, stream>>>(src2, dst2, cursor, psrc, pdst);
    mm128_dual_kernel<<<mmGrid, 256, 0, stream>>>(buf0, W2a, D2, b2a, ubuf, vbuf, N_NODES);
    hipMemsetAsync(agg, 0, NB * sizeof(unsigned), stream);
    edge_kernel<<<edgeGrid, 256, 0, stream>>>(ubuf, vbuf, x, psrc, pdst, WbT2, W2a + 256 * HID, agg);
    combine_kernel<<<(int)(NB / 256), 256, 0, stream>>>(agg, b2b, buf0, bufx2); // x2

    hipMemsetAsync(pooled, 0, 128 * 512 * sizeof(float), stream);
    pool_kernel<<<N_GRAPHS * 8, 256, 0, stream>>>(buf0, bufx2, batch, pooled);
    final_kernel<<<N_GRAPHS, 128, 0, stream>>>(pooled, batch, Wf1, bf1, Wf2, bf2, (float*)d_out);
}

// Round 7
// 838.337 us; speedup vs baseline: 4.4439x; 1.0027x over previous
//
#include <hip/hip_runtime.h>
#include <cstdint>

#define N_NODES 100000
#define N_EDGES 500000
#define N_GRAPHS 128
#define HID 128
#define SCAN_B ((N_NODES + 255) / 256)   // 391

typedef __attribute__((ext_vector_type(8))) short short8;
typedef __attribute__((ext_vector_type(4))) float f32x4;

// ---- monotone float<->uint encoding for max; enc==0 marks "never written" ----
__device__ __forceinline__ unsigned encf(float f) {
    unsigned u = __float_as_uint(f);
    return (u & 0x80000000u) ? ~u : (u | 0x80000000u);
}
__device__ __forceinline__ float decf(unsigned e) {
    unsigned u = (e & 0x80000000u) ? (e & 0x7FFFFFFFu) : ~e;
    return __uint_as_float(u);
}
// round-to-nearest-even fp32 -> bf16 (finite inputs only)
__device__ __forceinline__ unsigned pk_bf16(float a, float b) {
    unsigned ua = __float_as_uint(a);
    unsigned ub = __float_as_uint(b);
    ua = (ua + 0x7fffu + ((ua >> 16) & 1u)) >> 16;
    ub = (ub + 0x7fffu + ((ub >> 16) & 1u)) & 0xffff0000u;
    return ua | ub;
}
__device__ __forceinline__ ushort bf16r(float f) {
    unsigned u = __float_as_uint(f);
    return (ushort)((u + 0x7fffu + ((u >> 16) & 1u)) >> 16);
}

// ---- prep: fold key-embedding through W0; D = Wa[128:256]-Wa[0:128] ----
__global__ void prep_kernel(const float* __restrict__ W_enc, const float* __restrict__ b_enc,
                            const float* __restrict__ W0, const float* __restrict__ b0,
                            const float* __restrict__ W1a, const float* __restrict__ W2a,
                            float* __restrict__ wkey, float* __restrict__ bias0,
                            float* __restrict__ D1, float* __restrict__ D2) {
    int tid = threadIdx.x;
    if (tid < HID) {
        float wk = 0.f, bk = b0[tid];
        for (int k = 0; k < 32; ++k) {
            float w = W0[(15 + k) * HID + tid];
            wk += W_enc[k] * w;
            bk += b_enc[k] * w;
        }
        wkey[tid] = wk;
        bias0[tid] = bk;
    }
    for (int i = tid; i < HID * HID; i += blockDim.x) {
        D1[i] = W1a[HID * HID + i] - W1a[i];
        D2[i] = W2a[HID * HID + i] - W2a[i];
    }
}

// ---- transpose+convert W (fp32 [k][n], k,n<128) -> WT (bf16 [n][k]) ----
__global__ __launch_bounds__(256) void transp_kernel(const float* __restrict__ W,
                                                     ushort* __restrict__ WT) {
    int i = blockIdx.x * 256 + threadIdx.x;   // i = n*128 + k
    int n = i >> 7, k = i & 127;
    WT[i] = bf16r(W[k * HID + n]);
}

// ---- encoder: h = relu(features @ W0[0:15] + key*wkey + bias0) ----
__global__ __launch_bounds__(256) void encode_kernel(const float* __restrict__ x,
                                                     const float* __restrict__ W0,
                                                     const float* __restrict__ wkey,
                                                     const float* __restrict__ bias0,
                                                     float* __restrict__ h) {
    int n = blockIdx.x * 2 + (threadIdx.x >> 7);
    int j = threadIdx.x & 127;
    const float* xr = x + n * 16;
    float acc = bias0[j] + xr[0] * wkey[j];
#pragma unroll
    for (int f = 0; f < 15; ++f)
        acc = fmaf(xr[1 + f], W0[f * HID + j], acc);
    h[n * HID + j] = fmaxf(acc, 0.f);
}

// ---- dual MFMA (N x 128) @ (128 x 128) -> bf16: out_u = in@Wu ; out_v = in@Wv + bv ----
// h tile staged bf16 in LDS (34.8 KB -> 4 blocks/CU); A-frags kept in regs across
// both passes; W^T fragments read from global (32 KB, L1-resident).
__global__ __launch_bounds__(256, 4) void mm_mfma_dual_kernel(const float* __restrict__ in,
                                                              const ushort* __restrict__ WuT,
                                                              const ushort* __restrict__ WvT,
                                                              const float* __restrict__ bv,
                                                              ushort* __restrict__ outu,
                                                              ushort* __restrict__ outv, int nrows) {
    __shared__ ushort sH[128 * 136];   // 34816 B
    int tid = threadIdx.x;
    int n0 = blockIdx.x * 128;
#pragma unroll
    for (int q = 0; q < 16; ++q) {
        int idx = q * 256 + tid;
        int r = idx >> 5, c4 = idx & 31;
        int n = n0 + r;
        float4 vv = (n < nrows) ? ((const float4*)(in + (size_t)n * HID))[c4]
                                : make_float4(0.f, 0.f, 0.f, 0.f);
        uint2 o;
        o.x = pk_bf16(vv.x, vv.y);
        o.y = pk_bf16(vv.z, vv.w);
        *(uint2*)(sH + r * 136 + c4 * 4) = o;
    }
    __syncthreads();

    int lane = tid & 63, wv = tid >> 6;
    int l15 = lane & 15, quad = lane >> 4;

    // A fragments: rows wv*32 + rr*16 + l15, k = quad*8 + kc*32
    short8 afr[2][4];
#pragma unroll
    for (int rr = 0; rr < 2; ++rr) {
        const ushort* ab = sH + (wv * 32 + rr * 16 + l15) * 136 + quad * 8;
#pragma unroll
        for (int kc = 0; kc < 4; ++kc)
            afr[rr][kc] = *(const short8*)(ab + kc * 32);
    }

#pragma unroll
    for (int pass = 0; pass < 2; ++pass) {
        const ushort* WT = pass ? WvT : WuT;
        ushort* out = pass ? outv : outu;
        f32x4 acc[2][8];
#pragma unroll
        for (int rr = 0; rr < 2; ++rr)
#pragma unroll
            for (int ct = 0; ct < 8; ++ct) acc[rr][ct] = (f32x4){0.f, 0.f, 0.f, 0.f};
#pragma unroll
        for (int kc = 0; kc < 4; ++kc) {
#pragma unroll
            for (int ct = 0; ct < 8; ++ct) {
                short8 bfr = *(const short8*)(WT + (ct * 16 + l15) * 128 + quad * 8 + kc * 32);
                acc[0][ct] = __builtin_amdgcn_mfma_f32_16x16x32_bf16(afr[0][kc], bfr, acc[0][ct], 0, 0, 0);
                acc[1][ct] = __builtin_amdgcn_mfma_f32_16x16x32_bf16(afr[1][kc], bfr, acc[1][ct], 0, 0, 0);
            }
        }
        // D layout: col n = ct*16+l15, row m = wv*32 + rr*16 + quad*4 + reg
#pragma unroll
        for (int ct = 0; ct < 8; ++ct) {
            int n = ct * 16 + l15;
            float bb = pass ? bv[n] : 0.f;
#pragma unroll
            for (int rr = 0; rr < 2; ++rr) {
                int mbase = n0 + wv * 32 + rr * 16 + quad * 4;
#pragma unroll
                for (int reg = 0; reg < 4; ++reg) {
                    int m = mbase + reg;
                    if (m < nrows)
                        out[(size_t)m * HID + n] = bf16r(acc[rr][ct][reg] + bb);
                }
            }
        }
    }
}

// ---- CSR build: histogram -> hierarchical scan -> scatter ----
__global__ __launch_bounds__(256) void hist_kernel(const int* __restrict__ dst, int* __restrict__ cnt) {
    int e = blockIdx.x * 256 + threadIdx.x;
    if (e < N_EDGES) atomicAdd(&cnt[dst[e]], 1);
}

__global__ __launch_bounds__(256) void scan1_kernel(const int* __restrict__ cnt,
                                                    int* __restrict__ cursor,
                                                    int* __restrict__ partials) {
    __shared__ int tmp[256];
    int tid = threadIdx.x;
    int gid = blockIdx.x * 256 + tid;
    int v = (gid < N_NODES) ? cnt[gid] : 0;
    tmp[tid] = v;
    __syncthreads();
#pragma unroll
    for (int off = 1; off < 256; off <<= 1) {
        int t = (tid >= off) ? tmp[tid - off] : 0;
        __syncthreads();
        tmp[tid] += t;
        __syncthreads();
    }
    if (gid < N_NODES) cursor[gid] = tmp[tid] - v;   // exclusive
    if (tid == 255) partials[blockIdx.x] = tmp[255];
}

__global__ __launch_bounds__(512) void scan2_kernel(int* __restrict__ partials) {
    __shared__ int tmp[512];
    int tid = threadIdx.x;
    int v = (tid < SCAN_B) ? partials[tid] : 0;
    tmp[tid] = v;
    __syncthreads();
#pragma unroll
    for (int off = 1; off < 512; off <<= 1) {
        int t = (tid >= off) ? tmp[tid - off] : 0;
        __syncthreads();
        tmp[tid] += t;
        __syncthreads();
    }
    if (tid < SCAN_B) partials[tid] = tmp[tid] - v;  // exclusive
}

__global__ __launch_bounds__(256) void scan3_kernel(int* __restrict__ cursor,
                                                    const int* __restrict__ partials) {
    int gid = blockIdx.x * 256 + threadIdx.x;
    if (gid < N_NODES) cursor[gid] += partials[blockIdx.x];
}

__global__ __launch_bounds__(256) void scatter_kernel(const int* __restrict__ src,
                                                      const int* __restrict__ dst,
                                                      int* __restrict__ cursor,
                                                      int* __restrict__ psrc,
                                                      int* __restrict__ pdst) {
    int e = blockIdx.x * 256 + threadIdx.x;
    if (e < N_EDGES) {
        int d = dst[e];
        int pos = atomicAdd(&cursor[d], 1);
        psrc[pos] = src[e];
        pdst[pos] = d;
    }
}

// ---- edge conv: bf16 MFMA, 64-edge dst-sorted windows ----
__global__ __launch_bounds__(256, 3) void edge_kernel(const ushort* __restrict__ u,
                                                      const ushort* __restrict__ v,
                                                      const float* __restrict__ x,
                                                      const int* __restrict__ psrc,
                                                      const int* __restrict__ pdst,
                                                      const ushort* __restrict__ WbT,
                                                      const float* __restrict__ wlast,
                                                      unsigned* __restrict__ agg) {
    __shared__ ushort sWT[128 * 136];   // 34816 B: WbT[n][k] bf16, padded stride
    __shared__ ushort sU[64 * 136];     // 17408 B union: t[64][136] then msgT[128][68]
    __shared__ int sSrc[64], sDst[64];
    __shared__ float sKd[64];
    __shared__ int sPrev, sNext;
    int tid = threadIdx.x;
    int w0 = blockIdx.x * 64;

#pragma unroll
    for (int q = 0; q < 8; ++q) {
        int c = q * 256 + tid;
        int n = c >> 4, off = (c & 15) << 3;
        *(uint4*)(sWT + n * 136 + off) = *(const uint4*)(WbT + n * 128 + off);
    }
    if (tid < 64) {
        int e = w0 + tid;
        if (e >= N_EDGES) e = N_EDGES - 1;   // clamp: idempotent under max
        int s = psrc[e], d = pdst[e];
        sSrc[tid] = s;
        sDst[tid] = d;
        sKd[tid] = x[(size_t)s * 16] - x[(size_t)d * 16];
    }
    if (tid == 64) sPrev = (w0 > 0) ? pdst[w0 - 1] : -1;
    if (tid == 65) sNext = (w0 + 64 < N_EDGES) ? pdst[w0 + 64] : -1;
    __syncthreads();

    // phase 1: 4 threads/edge, 32 cols each
    {
        int eloc = tid >> 2;
        int kb = (tid & 3) << 5;
        int s = sSrc[eloc], d = sDst[eloc];
        float kd = sKd[eloc];
        const uint4* ur = (const uint4*)(u + (size_t)s * HID + kb);
        const uint4* vr = (const uint4*)(v + (size_t)d * HID + kb);
        uint4 uu[4], vv[4];
#pragma unroll
        for (int q = 0; q < 4; ++q) uu[q] = ur[q];
#pragma unroll
        for (int q = 0; q < 4; ++q) vv[q] = vr[q];
        const float4* wr4 = (const float4*)(wlast + kb);
        uint4* tout = (uint4*)(sU + eloc * 136 + kb);
#pragma unroll
        for (int q = 0; q < 4; ++q) {
            float4 wa = wr4[2 * q], wb = wr4[2 * q + 1];
            float w[8] = {wa.x, wa.y, wa.z, wa.w, wb.x, wb.y, wb.z, wb.w};
            unsigned pu[4] = {uu[q].x, uu[q].y, uu[q].z, uu[q].w};
            unsigned pv[4] = {vv[q].x, vv[q].y, vv[q].z, vv[q].w};
            unsigned pk[4];
#pragma unroll
            for (int p = 0; p < 4; ++p) {
                float a0 = __uint_as_float(pu[p] << 16) + __uint_as_float(pv[p] << 16);
                float a1 = __uint_as_float(pu[p] & 0xffff0000u) + __uint_as_float(pv[p] & 0xffff0000u);
                a0 = fmaf(kd, w[2 * p], a0);
                a1 = fmaf(kd, w[2 * p + 1], a1);
                a0 = a0 > 0.f ? a0 : 0.1f * a0;
                a1 = a1 > 0.f ? a1 : 0.1f * a1;
                pk[p] = pk_bf16(a0, a1);
            }
            uint4 o; o.x = pk[0]; o.y = pk[1]; o.z = pk[2]; o.w = pk[3];
            tout[q] = o;
        }
    }
    __syncthreads();

    // phase 2: MFMA. wave wv owns edges wv*16..+15; 8 col-tiles x 4 K-chunks
    int lane = tid & 63, wv = tid >> 6;
    int l15 = lane & 15, quad = lane >> 4;
    short8 afr[4];
    {
        const ushort* ab = sU + (wv * 16 + l15) * 136 + quad * 8;
#pragma unroll
        for (int kc = 0; kc < 4; ++kc)
            afr[kc] = *(const short8*)(ab + kc * 32);
    }
    f32x4 acc[8];
#pragma unroll
    for (int ct = 0; ct < 8; ++ct) {
        f32x4 a = {0.f, 0.f, 0.f, 0.f};
        const ushort* bb = sWT + (ct * 16 + l15) * 136 + quad * 8;
#pragma unroll
        for (int kc = 0; kc < 4; ++kc) {
            short8 bfr = *(const short8*)(bb + kc * 32);
            a = __builtin_amdgcn_mfma_f32_16x16x32_bf16(afr[kc], bfr, a, 0, 0, 0);
        }
        acc[ct] = a;
    }
    __syncthreads();   // all t reads done -> sU reusable

    // epilogue: msgT[col][edge] bf16, stride 68
#pragma unroll
    for (int ct = 0; ct < 8; ++ct) {
        uint2 pr;
        pr.x = pk_bf16(acc[ct][0], acc[ct][1]);
        pr.y = pk_bf16(acc[ct][2], acc[ct][3]);
        *(uint2*)(sU + (ct * 16 + l15) * 68 + wv * 16 + quad * 4) = pr;
    }
    __syncthreads();

    // phase 3: segmented max, 2 threads/col (half-window each)
    {
        int j = tid & 127;
        int h = tid >> 7;
        int eBeg = h * 32;
        const ushort* mrow = sU + j * 68 + eBeg;
        float vals[32];
#pragma unroll
        for (int q = 0; q < 8; ++q) {
            ushort4 mv = *(const ushort4*)(mrow + q * 4);
            vals[q * 4 + 0] = __uint_as_float((unsigned)mv.x << 16);
            vals[q * 4 + 1] = __uint_as_float((unsigned)mv.y << 16);
            vals[q * 4 + 2] = __uint_as_float((unsigned)mv.z << 16);
            vals[q * 4 + 3] = __uint_as_float((unsigned)mv.w << 16);
        }
        int prevD = (h == 0) ? sPrev : sDst[31];
        int nextD = (h == 0) ? sDst[32] : sNext;
        int cur = sDst[eBeg], rs = eBeg;
        float mx = vals[0];
        for (int e2 = 1; e2 < 32; ++e2) {
            int d = sDst[eBeg + e2];      // uniform across the half's lanes
            float vv2 = vals[e2];
            if (d != cur) {
                unsigned en = encf(mx);
                unsigned* ap = agg + (size_t)cur * HID + j;
                if (rs == eBeg && cur == prevD) atomicMax(ap, en);
                else *ap = en;
                cur = d; rs = eBeg + e2; mx = vv2;
            } else {
                mx = fmaxf(mx, vv2);
            }
        }
        unsigned en = encf(mx);
        unsigned* ap = agg + (size_t)cur * HID + j;
        if ((rs == eBeg && cur == prevD) || cur == nextD) atomicMax(ap, en);
        else *ap = en;
    }
}

// ---- combine: out = relu((agg? dec(agg)+bb : 0) + base) ----
__global__ __launch_bounds__(256) void combine_kernel(const unsigned* __restrict__ agg,
                                                      const float* __restrict__ bb,
                                                      const float* __restrict__ base,
                                                      float* __restrict__ out) {
    size_t i = (size_t)blockIdx.x * 256 + threadIdx.x;
    unsigned e = agg[i];
    int j = (int)(i & 127);
    float val = (e == 0u) ? 0.f : (decf(e) + bb[j]);
    out[i] = fmaxf(val + base[i], 0.f);
}

// ---- pooling: 8 slices per graph, atomic finalize ----
__global__ __launch_bounds__(256) void pool_kernel(const float* __restrict__ x1,
                                                   const float* __restrict__ x2,
                                                   const int* __restrict__ batch,
                                                   float* __restrict__ pooled) {
    int g = blockIdx.x >> 3, s = blockIdx.x & 7;
    int tid = threadIdx.x;
    int lo = 0, hi = N_NODES;
    while (lo < hi) { int mid = (lo + hi) >> 1; if (batch[mid] < g) lo = mid + 1; else hi = mid; }
    int start = lo;
    hi = N_NODES;
    while (lo < hi) { int mid = (lo + hi) >> 1; if (batch[mid] < g + 1) lo = mid + 1; else hi = mid; }
    int end = lo;
    int cnt = end - start;
    int b0 = start + (int)((long long)cnt * s / 8);
    int b1 = start + (int)((long long)cnt * (s + 1) / 8);
    if (b1 <= b0) return;
    const float* srcp = (tid < 128) ? (x1 + tid) : (x2 + (tid - 128));
    float mx = -INFINITY, sm = 0.f;
    for (int n = b0; n < b1; ++n) {
        float vv = srcp[(size_t)n * HID];
        mx = fmaxf(mx, vv);
        sm += vv;
    }
    atomicMax((unsigned*)pooled + (size_t)g * 512 + tid, encf(mx));
    atomicAdd(pooled + (size_t)g * 512 + 256 + tid, sm);
}

// ---- final MLP + log_softmax ----
__global__ __launch_bounds__(128) void final_kernel(const float* __restrict__ pooled,
                                                    const int* __restrict__ batch,
                                                    const float* __restrict__ Wf1,
                                                    const float* __restrict__ bf1,
                                                    const float* __restrict__ Wf2,
                                                    const float* __restrict__ bf2,
                                                    float* __restrict__ out) {
    __shared__ float sP[512];
    __shared__ float sH[128];
    int g = blockIdx.x, tid = threadIdx.x;
    int lo = 0, hi = N_NODES;
    while (lo < hi) { int mid = (lo + hi) >> 1; if (batch[mid] < g) lo = mid + 1; else hi = mid; }
    int start = lo;
    hi = N_NODES;
    while (lo < hi) { int mid = (lo + hi) >> 1; if (batch[mid] < g + 1) lo = mid + 1; else hi = mid; }
    int cnt = lo - start;
    float inv = 1.f / (float)(cnt > 1 ? cnt : 1);
#pragma unroll
    for (int q = 0; q < 4; ++q) {
        int idx = q * 128 + tid;
        float raw;
        if (idx < 256) {
            unsigned e = ((const unsigned*)pooled)[(size_t)g * 512 + idx];
            raw = (e == 0u) ? 0.f : decf(e);
        } else {
            raw = pooled[(size_t)g * 512 + idx] * inv;
        }
        sP[idx] = raw;
    }
    __syncthreads();
    float acc = bf1[tid];
    for (int k = 0; k < 512; ++k) acc = fmaf(sP[k], Wf1[k * HID + tid], acc);
    sH[tid] = fmaxf(acc, 0.f);
    __syncthreads();
    if (tid < 2) {
        float l = bf2[tid];
        for (int k = 0; k < 128; ++k) l = fmaf(sH[k], Wf2[k * 2 + tid], l);
        sP[tid] = l;
    }
    __syncthreads();
    if (tid == 0) {
        float l0 = sP[0], l1 = sP[1];
        float m = fmaxf(l0, l1);
        float ls = m + logf(expf(l0 - m) + expf(l1 - m));
        out[g * 2 + 0] = l0 - ls;
        out[g * 2 + 1] = l1 - ls;
    }
}

extern "C" void kernel_launch(void* const* d_in, const int* in_sizes, int n_in,
                              void* d_out, int out_size, void* d_ws, size_t ws_size,
                              hipStream_t stream) {
    const float* x     = (const float*)d_in[0];
    const float* W_enc = (const float*)d_in[1];
    const float* b_enc = (const float*)d_in[2];
    const float* W0    = (const float*)d_in[3];
    const float* b0    = (const float*)d_in[4];
    const float* W1a   = (const float*)d_in[5];
    const float* b1a   = (const float*)d_in[6];
    const float* W1b   = (const float*)d_in[7];
    const float* b1b   = (const float*)d_in[8];
    const float* W2a   = (const float*)d_in[9];
    const float* b2a   = (const float*)d_in[10];
    const float* W2b   = (const float*)d_in[11];
    const float* b2b   = (const float*)d_in[12];
    const float* Wf1   = (const float*)d_in[13];
    const float* bf1   = (const float*)d_in[14];
    const float* Wf2   = (const float*)d_in[15];
    const float* bf2   = (const float*)d_in[16];
    const int* src1    = (const int*)d_in[17];
    const int* dst1    = (const int*)d_in[18];
    const int* src2    = (const int*)d_in[19];
    const int* dst2    = (const int*)d_in[20];
    const int* batch   = (const int*)d_in[21];

    const size_t NB = (size_t)N_NODES * HID;     // 12.8M elements
    float* buf0  = (float*)d_ws;                 // h -> x1 (in place)
    float* bufx2 = buf0 + NB;                    // x2
    unsigned* agg = (unsigned*)(bufx2 + NB);     // encoded segment-max
    ushort* ubuf = (ushort*)(agg + NB);          // u bf16
    ushort* vbuf = ubuf + NB;                    // v bf16
    ushort* WbT1 = vbuf + NB;                    // 16384 each below
    ushort* WbT2 = WbT1 + HID * HID;
    ushort* WuT1 = WbT2 + HID * HID;
    ushort* WvT1 = WuT1 + HID * HID;
    ushort* WuT2 = WvT1 + HID * HID;
    ushort* WvT2 = WuT2 + HID * HID;
    float* wkey  = (float*)(WvT2 + HID * HID);
    float* bias0 = wkey + 128;
    float* D1    = bias0 + 128;
    float* D2    = D1 + HID * HID;
    float* pooled = D2 + HID * HID;              // 128*512 fp32
    int* cnt    = (int*)(pooled + 128 * 512);    // 100000
    int* cursor = cnt + N_NODES;                 // 100000
    int* partials = cursor + N_NODES;            // 512
    int* psrc   = partials + 512;                // 500000
    int* pdst   = psrc + N_EDGES;                // 500000

    const int histGrid = (N_EDGES + 255) / 256;
    const int edgeGrid = (N_EDGES + 63) / 64;    // 7813 windows of 64
    const int mmGrid   = (N_NODES + 127) / 128;  // 782

    prep_kernel<<<1, 256, 0, stream>>>(W_enc, b_enc, W0, b0, W1a, W2a, wkey, bias0, D1, D2);
    transp_kernel<<<64, 256, 0, stream>>>(W1b, WbT1);
    transp_kernel<<<64, 256, 0, stream>>>(W2b, WbT2);
    transp_kernel<<<64, 256, 0, stream>>>(W1a, WuT1);   // A-part of W1a (rows 0..127)
    transp_kernel<<<64, 256, 0, stream>>>(D1, WvT1);
    transp_kernel<<<64, 256, 0, stream>>>(W2a, WuT2);
    transp_kernel<<<64, 256, 0, stream>>>(D2, WvT2);
    encode_kernel<<<N_NODES / 2, 256, 0, stream>>>(x, W0, wkey, bias0, buf0);

    // ---- layer 1 ----
    hipMemsetAsync(cnt, 0, N_NODES * sizeof(int), stream);
    hist_kernel<<<histGrid, 256, 0, stream>>>(dst1, cnt);
    scan1_kernel<<<SCAN_B, 256, 0, stream>>>(cnt, cursor, partials);
    scan2_kernel<<<1, 512, 0, stream>>>(partials);
    scan3_kernel<<<SCAN_B, 256, 0, stream>>>(cursor, partials);
    scatter_kernel<<<histGrid, 256, 0, stream>>>(src1, dst1, cursor, psrc, pdst);
    mm_mfma_dual_kernel<<<mmGrid, 256, 0, stream>>>(buf0, WuT1, WvT1, b1a, ubuf, vbuf, N_NODES);
    hipMemsetAsync(agg, 0, NB * sizeof(unsigned), stream);
    edge_kernel<<<edgeGrid, 256, 0, stream>>>(ubuf, vbuf, x, psrc, pdst, WbT1, W1a + 256 * HID, agg);
    combine_kernel<<<(int)(NB / 256), 256, 0, stream>>>(agg, b1b, buf0, buf0);   // x1 in place

    // ---- layer 2 ----
    hipMemsetAsync(cnt, 0, N_NODES * sizeof(int), stream);
    hist_kernel<<<histGrid, 256, 0, stream>>>(dst2, cnt);
    scan1_kernel<<<SCAN_B, 256, 0, stream>>>(cnt, cursor, partials);
    scan2_kernel<<<1, 512, 0, stream>>>(partials);
    scan3_kernel<<<SCAN_B, 256, 0, stream>>>(cursor, partials);
    scatter_kernel<<<histGrid, 256, 0, stream>>>(src2, dst2, cursor, psrc, pdst);
    mm_mfma_dual_kernel<<<mmGrid, 256, 0, stream>>>(buf0, WuT2, WvT2, b2a, ubuf, vbuf, N_NODES);
    hipMemsetAsync(agg, 0, NB * sizeof(unsigned), stream);
    edge_kernel<<<edgeGrid, 256, 0, stream>>>(ubuf, vbuf, x, psrc, pdst, WbT2, W2a + 256 * HID, agg);
    combine_kernel<<<(int)(NB / 256), 256, 0, stream>>>(agg, b2b, buf0, bufx2); // x2

    hipMemsetAsync(pooled, 0, 128 * 512 * sizeof(float), stream);
    pool_kernel<<<N_GRAPHS * 8, 256, 0, stream>>>(buf0, bufx2, batch, pooled);
    final_kernel<<<N_GRAPHS, 128, 0, stream>>>(pooled, batch, Wf1, bf1, Wf2, bf2, (float*)d_out);
}

// Round 8
// 700.981 us; speedup vs baseline: 5.3147x; 1.1959x over previous
//
#include <hip/hip_runtime.h>
#include <cstdint>

#define N_NODES 100000
#define N_EDGES 500000
#define N_GRAPHS 128
#define HID 128
#define SCAN_B ((N_NODES + 255) / 256)   // 391

typedef __attribute__((ext_vector_type(8))) short short8;
typedef __attribute__((ext_vector_type(4))) float f32x4;

// ---- monotone float<->uint encoding for max; enc==0 marks "never written" ----
__device__ __forceinline__ unsigned encf(float f) {
    unsigned u = __float_as_uint(f);
    return (u & 0x80000000u) ? ~u : (u | 0x80000000u);
}
__device__ __forceinline__ float decf(unsigned e) {
    unsigned u = (e & 0x80000000u) ? (e & 0x7FFFFFFFu) : ~e;
    return __uint_as_float(u);
}
// round-to-nearest-even fp32 -> bf16 (finite inputs only)
__device__ __forceinline__ unsigned pk_bf16(float a, float b) {
    unsigned ua = __float_as_uint(a);
    unsigned ub = __float_as_uint(b);
    ua = (ua + 0x7fffu + ((ua >> 16) & 1u)) >> 16;
    ub = (ub + 0x7fffu + ((ub >> 16) & 1u)) & 0xffff0000u;
    return ua | ub;
}
__device__ __forceinline__ ushort bf16r(float f) {
    unsigned u = __float_as_uint(f);
    return (ushort)((u + 0x7fffu + ((u >> 16) & 1u)) >> 16);
}
__device__ __forceinline__ float bf2f(ushort h) {
    return __uint_as_float((unsigned)h << 16);
}

// ---- prep: fold key-embedding through W0; D = Wa[128:256]-Wa[0:128] ----
__global__ void prep_kernel(const float* __restrict__ W_enc, const float* __restrict__ b_enc,
                            const float* __restrict__ W0, const float* __restrict__ b0,
                            const float* __restrict__ W1a, const float* __restrict__ W2a,
                            float* __restrict__ wkey, float* __restrict__ bias0,
                            float* __restrict__ D1, float* __restrict__ D2) {
    int tid = threadIdx.x;
    if (tid < HID) {
        float wk = 0.f, bk = b0[tid];
        for (int k = 0; k < 32; ++k) {
            float w = W0[(15 + k) * HID + tid];
            wk += W_enc[k] * w;
            bk += b_enc[k] * w;
        }
        wkey[tid] = wk;
        bias0[tid] = bk;
    }
    for (int i = tid; i < HID * HID; i += blockDim.x) {
        D1[i] = W1a[HID * HID + i] - W1a[i];
        D2[i] = W2a[HID * HID + i] - W2a[i];
    }
}

// ---- transpose+convert 6 weight mats (fp32 [k][n]) -> WT (bf16 [n][k]), one launch ----
__global__ __launch_bounds__(256) void transp6_kernel(const float* __restrict__ s0,
                                                      const float* __restrict__ s1,
                                                      const float* __restrict__ s2,
                                                      const float* __restrict__ s3,
                                                      const float* __restrict__ s4,
                                                      const float* __restrict__ s5,
                                                      ushort* __restrict__ WT) {
    int m = blockIdx.x >> 6;
    const float* W = m == 0 ? s0 : m == 1 ? s1 : m == 2 ? s2 : m == 3 ? s3 : m == 4 ? s4 : s5;
    int i = (blockIdx.x & 63) * 256 + threadIdx.x;   // i = n*128 + k
    int n = i >> 7, k = i & 127;
    WT[m * HID * HID + i] = bf16r(W[k * HID + n]);
}

// ---- encoder: h = relu(features @ W0[0:15] + key*wkey + bias0) -> bf16 ----
__global__ __launch_bounds__(256) void encode_kernel(const float* __restrict__ x,
                                                     const float* __restrict__ W0,
                                                     const float* __restrict__ wkey,
                                                     const float* __restrict__ bias0,
                                                     ushort* __restrict__ h) {
    int n = blockIdx.x * 2 + (threadIdx.x >> 7);
    int j = threadIdx.x & 127;
    const float* xr = x + n * 16;
    float acc = bias0[j] + xr[0] * wkey[j];
#pragma unroll
    for (int f = 0; f < 15; ++f)
        acc = fmaf(xr[1 + f], W0[f * HID + j], acc);
    h[n * HID + j] = bf16r(fmaxf(acc, 0.f));
}

// ---- dual MFMA (N x 128 bf16) @ (128 x 128) -> bf16: out_u = in@Wu ; out_v = in@Wv + bv ----
// Epilogue re-stages D through LDS for coalesced 16B stores (fixes 2.6x write amp).
__global__ __launch_bounds__(256, 4) void mm_mfma_dual_kernel(const ushort* __restrict__ in,
                                                              const ushort* __restrict__ WuT,
                                                              const ushort* __restrict__ WvT,
                                                              const float* __restrict__ bv,
                                                              ushort* __restrict__ outu,
                                                              ushort* __restrict__ outv, int nrows) {
    __shared__ ushort sH[128 * 136];   // 34816 B; holds A-tile, then reused for D-restage
    int tid = threadIdx.x;
    int n0 = blockIdx.x * 128;
    // stage bf16 input tile: 2048 16B chunks
#pragma unroll
    for (int q = 0; q < 8; ++q) {
        int c = q * 256 + tid;
        int r = c >> 4, off = (c & 15) << 3;
        int n = n0 + r;
        uint4 vv;
        if (n < nrows) vv = *(const uint4*)(in + (size_t)n * HID + off);
        else vv = make_uint4(0, 0, 0, 0);
        *(uint4*)(sH + r * 136 + off) = vv;
    }
    __syncthreads();

    int lane = tid & 63, wv = tid >> 6;
    int l15 = lane & 15, quad = lane >> 4;

    // A fragments: rows wv*32 + rr*16 + l15, k = quad*8 + kc*32 (kept in regs across passes)
    short8 afr[2][4];
#pragma unroll
    for (int rr = 0; rr < 2; ++rr) {
        const ushort* ab = sH + (wv * 32 + rr * 16 + l15) * 136 + quad * 8;
#pragma unroll
        for (int kc = 0; kc < 4; ++kc)
            afr[rr][kc] = *(const short8*)(ab + kc * 32);
    }

#pragma unroll
    for (int pass = 0; pass < 2; ++pass) {
        const ushort* WT = pass ? WvT : WuT;
        ushort* out = pass ? outv : outu;
        f32x4 acc[2][8];
#pragma unroll
        for (int rr = 0; rr < 2; ++rr)
#pragma unroll
            for (int ct = 0; ct < 8; ++ct) acc[rr][ct] = (f32x4){0.f, 0.f, 0.f, 0.f};
#pragma unroll
        for (int kc = 0; kc < 4; ++kc) {
#pragma unroll
            for (int ct = 0; ct < 8; ++ct) {
                short8 bfr = *(const short8*)(WT + (ct * 16 + l15) * 128 + quad * 8 + kc * 32);
                acc[0][ct] = __builtin_amdgcn_mfma_f32_16x16x32_bf16(afr[0][kc], bfr, acc[0][ct], 0, 0, 0);
                acc[1][ct] = __builtin_amdgcn_mfma_f32_16x16x32_bf16(afr[1][kc], bfr, acc[1][ct], 0, 0, 0);
            }
        }
        __syncthreads();   // prior readers of sH done (afr loads / pass0 restage reads)
        // D layout: col n = ct*16+l15, row m = wv*32 + rr*16 + quad*4 + reg
#pragma unroll
        for (int ct = 0; ct < 8; ++ct) {
            int col = ct * 16 + l15;
            float bb = pass ? bv[col] : 0.f;
#pragma unroll
            for (int rr = 0; rr < 2; ++rr) {
                int rowb = wv * 32 + rr * 16 + quad * 4;
#pragma unroll
                for (int reg = 0; reg < 4; ++reg)
                    sH[(rowb + reg) * 136 + col] = bf16r(acc[rr][ct][reg] + bb);
            }
        }
        __syncthreads();
        // coalesced 16B stores
#pragma unroll
        for (int q = 0; q < 8; ++q) {
            int c = q * 256 + tid;
            int r = c >> 4, off = (c & 15) << 3;
            int m = n0 + r;
            if (m < nrows)
                *(uint4*)(out + (size_t)m * HID + off) = *(const uint4*)(sH + r * 136 + off);
        }
    }
}

// ---- CSR build: histogram -> hierarchical scan -> scatter ----
__global__ __launch_bounds__(256) void hist_kernel(const int* __restrict__ dst, int* __restrict__ cnt) {
    int e = blockIdx.x * 256 + threadIdx.x;
    if (e < N_EDGES) atomicAdd(&cnt[dst[e]], 1);
}

__global__ __launch_bounds__(256) void scan1_kernel(const int* __restrict__ cnt,
                                                    int* __restrict__ cursor,
                                                    int* __restrict__ partials) {
    __shared__ int tmp[256];
    int tid = threadIdx.x;
    int gid = blockIdx.x * 256 + tid;
    int v = (gid < N_NODES) ? cnt[gid] : 0;
    tmp[tid] = v;
    __syncthreads();
#pragma unroll
    for (int off = 1; off < 256; off <<= 1) {
        int t = (tid >= off) ? tmp[tid - off] : 0;
        __syncthreads();
        tmp[tid] += t;
        __syncthreads();
    }
    if (gid < N_NODES) cursor[gid] = tmp[tid] - v;   // exclusive
    if (tid == 255) partials[blockIdx.x] = tmp[255];
}

__global__ __launch_bounds__(512) void scan2_kernel(int* __restrict__ partials) {
    __shared__ int tmp[512];
    int tid = threadIdx.x;
    int v = (tid < SCAN_B) ? partials[tid] : 0;
    tmp[tid] = v;
    __syncthreads();
#pragma unroll
    for (int off = 1; off < 512; off <<= 1) {
        int t = (tid >= off) ? tmp[tid - off] : 0;
        __syncthreads();
        tmp[tid] += t;
        __syncthreads();
    }
    if (tid < SCAN_B) partials[tid] = tmp[tid] - v;  // exclusive
}

__global__ __launch_bounds__(256) void scan3_kernel(int* __restrict__ cursor,
                                                    const int* __restrict__ partials) {
    int gid = blockIdx.x * 256 + threadIdx.x;
    if (gid < N_NODES) cursor[gid] += partials[blockIdx.x];
}

// scatter writes packed (src,dst) pairs -> one 8B random write instead of two 4B
__global__ __launch_bounds__(256) void scatter_kernel(const int* __restrict__ src,
                                                      const int* __restrict__ dst,
                                                      int* __restrict__ cursor,
                                                      int2* __restrict__ pedge) {
    int e = blockIdx.x * 256 + threadIdx.x;
    if (e < N_EDGES) {
        int d = dst[e];
        int pos = atomicAdd(&cursor[d], 1);
        pedge[pos] = make_int2(src[e], d);
    }
}

// ---- edge conv: bf16 MFMA, 64-edge dst-sorted windows ----
__global__ __launch_bounds__(256, 3) void edge_kernel(const ushort* __restrict__ u,
                                                      const ushort* __restrict__ v,
                                                      const float* __restrict__ x,
                                                      const int2* __restrict__ pedge,
                                                      const ushort* __restrict__ WbT,
                                                      const float* __restrict__ wlast,
                                                      unsigned* __restrict__ agg) {
    __shared__ ushort sWT[128 * 136];   // 34816 B: WbT[n][k] bf16, padded stride
    __shared__ ushort sU[64 * 136];     // 17408 B union: t[64][136] then msgT[128][68]
    __shared__ int sSrc[64], sDst[64];
    __shared__ float sKd[64];
    __shared__ int sPrev, sNext;
    int tid = threadIdx.x;
    int w0 = blockIdx.x * 64;

#pragma unroll
    for (int q = 0; q < 8; ++q) {
        int c = q * 256 + tid;
        int n = c >> 4, off = (c & 15) << 3;
        *(uint4*)(sWT + n * 136 + off) = *(const uint4*)(WbT + n * 128 + off);
    }
    if (tid < 64) {
        int e = w0 + tid;
        if (e >= N_EDGES) e = N_EDGES - 1;   // clamp: idempotent under max
        int2 sd = pedge[e];
        sSrc[tid] = sd.x;
        sDst[tid] = sd.y;
        sKd[tid] = x[(size_t)sd.x * 16] - x[(size_t)sd.y * 16];
    }
    if (tid == 64) sPrev = (w0 > 0) ? pedge[w0 - 1].y : -1;
    if (tid == 65) sNext = (w0 + 64 < N_EDGES) ? pedge[w0 + 64].y : -1;
    __syncthreads();

    // phase 1: 4 threads/edge, 32 cols each
    {
        int eloc = tid >> 2;
        int kb = (tid & 3) << 5;
        int s = sSrc[eloc], d = sDst[eloc];
        float kd = sKd[eloc];
        const uint4* ur = (const uint4*)(u + (size_t)s * HID + kb);
        const uint4* vr = (const uint4*)(v + (size_t)d * HID + kb);
        uint4 uu[4], vv[4];
#pragma unroll
        for (int q = 0; q < 4; ++q) uu[q] = ur[q];
#pragma unroll
        for (int q = 0; q < 4; ++q) vv[q] = vr[q];
        const float4* wr4 = (const float4*)(wlast + kb);
        uint4* tout = (uint4*)(sU + eloc * 136 + kb);
#pragma unroll
        for (int q = 0; q < 4; ++q) {
            float4 wa = wr4[2 * q], wb = wr4[2 * q + 1];
            float w[8] = {wa.x, wa.y, wa.z, wa.w, wb.x, wb.y, wb.z, wb.w};
            unsigned pu[4] = {uu[q].x, uu[q].y, uu[q].z, uu[q].w};
            unsigned pv[4] = {vv[q].x, vv[q].y, vv[q].z, vv[q].w};
            unsigned pk[4];
#pragma unroll
            for (int p = 0; p < 4; ++p) {
                float a0 = __uint_as_float(pu[p] << 16) + __uint_as_float(pv[p] << 16);
                float a1 = __uint_as_float(pu[p] & 0xffff0000u) + __uint_as_float(pv[p] & 0xffff0000u);
                a0 = fmaf(kd, w[2 * p], a0);
                a1 = fmaf(kd, w[2 * p + 1], a1);
                a0 = a0 > 0.f ? a0 : 0.1f * a0;
                a1 = a1 > 0.f ? a1 : 0.1f * a1;
                pk[p] = pk_bf16(a0, a1);
            }
            uint4 o; o.x = pk[0]; o.y = pk[1]; o.z = pk[2]; o.w = pk[3];
            tout[q] = o;
        }
    }
    __syncthreads();

    // phase 2: MFMA. wave wv owns edges wv*16..+15; 8 col-tiles x 4 K-chunks
    int lane = tid & 63, wv = tid >> 6;
    int l15 = lane & 15, quad = lane >> 4;
    short8 afr[4];
    {
        const ushort* ab = sU + (wv * 16 + l15) * 136 + quad * 8;
#pragma unroll
        for (int kc = 0; kc < 4; ++kc)
            afr[kc] = *(const short8*)(ab + kc * 32);
    }
    f32x4 acc[8];
#pragma unroll
    for (int ct = 0; ct < 8; ++ct) {
        f32x4 a = {0.f, 0.f, 0.f, 0.f};
        const ushort* bb = sWT + (ct * 16 + l15) * 136 + quad * 8;
#pragma unroll
        for (int kc = 0; kc < 4; ++kc) {
            short8 bfr = *(const short8*)(bb + kc * 32);
            a = __builtin_amdgcn_mfma_f32_16x16x32_bf16(afr[kc], bfr, a, 0, 0, 0);
        }
        acc[ct] = a;
    }
    __syncthreads();   // all t reads done -> sU reusable

    // epilogue: msgT[col][edge] bf16, stride 68
#pragma unroll
    for (int ct = 0; ct < 8; ++ct) {
        uint2 pr;
        pr.x = pk_bf16(acc[ct][0], acc[ct][1]);
        pr.y = pk_bf16(acc[ct][2], acc[ct][3]);
        *(uint2*)(sU + (ct * 16 + l15) * 68 + wv * 16 + quad * 4) = pr;
    }
    __syncthreads();

    // phase 3: segmented max, 2 threads/col (half-window each)
    {
        int j = tid & 127;
        int h = tid >> 7;
        int eBeg = h * 32;
        const ushort* mrow = sU + j * 68 + eBeg;
        float vals[32];
#pragma unroll
        for (int q = 0; q < 8; ++q) {
            ushort4 mv = *(const ushort4*)(mrow + q * 4);
            vals[q * 4 + 0] = bf2f(mv.x);
            vals[q * 4 + 1] = bf2f(mv.y);
            vals[q * 4 + 2] = bf2f(mv.z);
            vals[q * 4 + 3] = bf2f(mv.w);
        }
        int prevD = (h == 0) ? sPrev : sDst[31];
        int nextD = (h == 0) ? sDst[32] : sNext;
        int cur = sDst[eBeg], rs = eBeg;
        float mx = vals[0];
        for (int e2 = 1; e2 < 32; ++e2) {
            int d = sDst[eBeg + e2];      // uniform across the half's lanes
            float vv2 = vals[e2];
            if (d != cur) {
                unsigned en = encf(mx);
                unsigned* ap = agg + (size_t)cur * HID + j;
                if (rs == eBeg && cur == prevD) atomicMax(ap, en);
                else *ap = en;
                cur = d; rs = eBeg + e2; mx = vv2;
            } else {
                mx = fmaxf(mx, vv2);
            }
        }
        unsigned en = encf(mx);
        unsigned* ap = agg + (size_t)cur * HID + j;
        if ((rs == eBeg && cur == prevD) || cur == nextD) atomicMax(ap, en);
        else *ap = en;
    }
}

// ---- combine: out = relu((agg? dec(agg)+bb : 0) + base), bf16 in/out, 4 elems/thread ----
__global__ __launch_bounds__(256) void combine_kernel(const unsigned* __restrict__ agg,
                                                      const float* __restrict__ bb,
                                                      const ushort* __restrict__ base,
                                                      ushort* __restrict__ out) {
    size_t i = ((size_t)blockIdx.x * 256 + threadIdx.x) * 4;
    uint4 e4 = *(const uint4*)(agg + i);
    ushort4 b4 = *(const ushort4*)(base + i);
    int j = (int)(i & 127);
    float4 bbv = *(const float4*)(bb + j);
    float r0 = (e4.x == 0u) ? 0.f : (decf(e4.x) + bbv.x);
    float r1 = (e4.y == 0u) ? 0.f : (decf(e4.y) + bbv.y);
    float r2 = (e4.z == 0u) ? 0.f : (decf(e4.z) + bbv.z);
    float r3 = (e4.w == 0u) ? 0.f : (decf(e4.w) + bbv.w);
    ushort4 o;
    o.x = bf16r(fmaxf(r0 + bf2f(b4.x), 0.f));
    o.y = bf16r(fmaxf(r1 + bf2f(b4.y), 0.f));
    o.z = bf16r(fmaxf(r2 + bf2f(b4.z), 0.f));
    o.w = bf16r(fmaxf(r3 + bf2f(b4.w), 0.f));
    *(ushort4*)(out + i) = o;
}

// ---- pooling: 8 slices per graph, atomic finalize; bf16 inputs ----
__global__ __launch_bounds__(256) void pool_kernel(const ushort* __restrict__ x1,
                                                   const ushort* __restrict__ x2,
                                                   const int* __restrict__ batch,
                                                   float* __restrict__ pooled) {
    int g = blockIdx.x >> 3, s = blockIdx.x & 7;
    int tid = threadIdx.x;
    int lo = 0, hi = N_NODES;
    while (lo < hi) { int mid = (lo + hi) >> 1; if (batch[mid] < g) lo = mid + 1; else hi = mid; }
    int start = lo;
    hi = N_NODES;
    while (lo < hi) { int mid = (lo + hi) >> 1; if (batch[mid] < g + 1) lo = mid + 1; else hi = mid; }
    int end = lo;
    int cnt = end - start;
    int b0 = start + (int)((long long)cnt * s / 8);
    int b1 = start + (int)((long long)cnt * (s + 1) / 8);
    if (b1 <= b0) return;
    const ushort* srcp = (tid < 128) ? (x1 + tid) : (x2 + (tid - 128));
    float mx = -INFINITY, sm = 0.f;
    for (int n = b0; n < b1; ++n) {
        float vv = bf2f(srcp[(size_t)n * HID]);
        mx = fmaxf(mx, vv);
        sm += vv;
    }
    atomicMax((unsigned*)pooled + (size_t)g * 512 + tid, encf(mx));
    atomicAdd(pooled + (size_t)g * 512 + 256 + tid, sm);
}

// ---- final MLP + log_softmax ----
__global__ __launch_bounds__(128) void final_kernel(const float* __restrict__ pooled,
                                                    const int* __restrict__ batch,
                                                    const float* __restrict__ Wf1,
                                                    const float* __restrict__ bf1,
                                                    const float* __restrict__ Wf2,
                                                    const float* __restrict__ bf2,
                                                    float* __restrict__ out) {
    __shared__ float sP[512];
    __shared__ float sH[128];
    int g = blockIdx.x, tid = threadIdx.x;
    int lo = 0, hi = N_NODES;
    while (lo < hi) { int mid = (lo + hi) >> 1; if (batch[mid] < g) lo = mid + 1; else hi = mid; }
    int start = lo;
    hi = N_NODES;
    while (lo < hi) { int mid = (lo + hi) >> 1; if (batch[mid] < g + 1) lo = mid + 1; else hi = mid; }
    int cnt = lo - start;
    float inv = 1.f / (float)(cnt > 1 ? cnt : 1);
#pragma unroll
    for (int q = 0; q < 4; ++q) {
        int idx = q * 128 + tid;
        float raw;
        if (idx < 256) {
            unsigned e = ((const unsigned*)pooled)[(size_t)g * 512 + idx];
            raw = (e == 0u) ? 0.f : decf(e);
        } else {
            raw = pooled[(size_t)g * 512 + idx] * inv;
        }
        sP[idx] = raw;
    }
    __syncthreads();
    float acc = bf1[tid];
    for (int k = 0; k < 512; ++k) acc = fmaf(sP[k], Wf1[k * HID + tid], acc);
    sH[tid] = fmaxf(acc, 0.f);
    __syncthreads();
    if (tid < 2) {
        float l = bf2[tid];
        for (int k = 0; k < 128; ++k) l = fmaf(sH[k], Wf2[k * 2 + tid], l);
        sP[tid] = l;
    }
    __syncthreads();
    if (tid == 0) {
        float l0 = sP[0], l1 = sP[1];
        float m = fmaxf(l0, l1);
        float ls = m + logf(expf(l0 - m) + expf(l1 - m));
        out[g * 2 + 0] = l0 - ls;
        out[g * 2 + 1] = l1 - ls;
    }
}

extern "C" void kernel_launch(void* const* d_in, const int* in_sizes, int n_in,
                              void* d_out, int out_size, void* d_ws, size_t ws_size,
                              hipStream_t stream) {
    const float* x     = (const float*)d_in[0];
    const float* W_enc = (const float*)d_in[1];
    const float* b_enc = (const float*)d_in[2];
    const float* W0    = (const float*)d_in[3];
    const float* b0    = (const float*)d_in[4];
    const float* W1a   = (const float*)d_in[5];
    const float* b1a   = (const float*)d_in[6];
    const float* W1b   = (const float*)d_in[7];
    const float* b1b   = (const float*)d_in[8];
    const float* W2a   = (const float*)d_in[9];
    const float* b2a   = (const float*)d_in[10];
    const float* W2b   = (const float*)d_in[11];
    const float* b2b   = (const float*)d_in[12];
    const float* Wf1   = (const float*)d_in[13];
    const float* bf1   = (const float*)d_in[14];
    const float* Wf2   = (const float*)d_in[15];
    const float* bf2   = (const float*)d_in[16];
    const int* src1    = (const int*)d_in[17];
    const int* dst1    = (const int*)d_in[18];
    const int* src2    = (const int*)d_in[19];
    const int* dst2    = (const int*)d_in[20];
    const int* batch   = (const int*)d_in[21];

    const size_t NB = (size_t)N_NODES * HID;     // 12.8M elements
    ushort* hbuf  = (ushort*)d_ws;               // h -> x1 (in place, bf16)
    ushort* x2buf = hbuf + NB;                   // x2 bf16
    unsigned* agg = (unsigned*)(x2buf + NB);     // encoded segment-max
    ushort* ubuf = (ushort*)(agg + NB);          // u bf16
    ushort* vbuf = ubuf + NB;                    // v bf16
    ushort* WT   = vbuf + NB;                    // 6 x 16384 bf16: Wb1,Wb2,Wu1,Wv1,Wu2,Wv2
    ushort* WbT1 = WT;
    ushort* WbT2 = WT + 1 * HID * HID;
    ushort* WuT1 = WT + 2 * HID * HID;
    ushort* WvT1 = WT + 3 * HID * HID;
    ushort* WuT2 = WT + 4 * HID * HID;
    ushort* WvT2 = WT + 5 * HID * HID;
    float* wkey  = (float*)(WT + 6 * HID * HID);
    float* bias0 = wkey + 128;
    float* D1    = bias0 + 128;
    float* D2    = D1 + HID * HID;
    float* pooled = D2 + HID * HID;              // 128*512 fp32
    int* cnt    = (int*)(pooled + 128 * 512);    // 100000
    int* cursor = cnt + N_NODES;                 // 100000
    int* partials = cursor + N_NODES;            // 512
    int2* pedge = (int2*)(partials + 512);       // 500000 pairs

    const int histGrid = (N_EDGES + 255) / 256;
    const int edgeGrid = (N_EDGES + 63) / 64;    // 7813 windows of 64
    const int mmGrid   = (N_NODES + 127) / 128;  // 782

    prep_kernel<<<1, 256, 0, stream>>>(W_enc, b_enc, W0, b0, W1a, W2a, wkey, bias0, D1, D2);
    transp6_kernel<<<384, 256, 0, stream>>>(W1b, W2b, W1a, D1, W2a, D2, WT);
    encode_kernel<<<N_NODES / 2, 256, 0, stream>>>(x, W0, wkey, bias0, hbuf);

    // ---- layer 1 ----
    hipMemsetAsync(cnt, 0, N_NODES * sizeof(int), stream);
    hist_kernel<<<histGrid, 256, 0, stream>>>(dst1, cnt);
    scan1_kernel<<<SCAN_B, 256, 0, stream>>>(cnt, cursor, partials);
    scan2_kernel<<<1, 512, 0, stream>>>(partials);
    scan3_kernel<<<SCAN_B, 256, 0, stream>>>(cursor, partials);
    scatter_kernel<<<histGrid, 256, 0, stream>>>(src1, dst1, cursor, pedge);
    mm_mfma_dual_kernel<<<mmGrid, 256, 0, stream>>>(hbuf, WuT1, WvT1, b1a, ubuf, vbuf, N_NODES);
    hipMemsetAsync(agg, 0, NB * sizeof(unsigned), stream);
    edge_kernel<<<edgeGrid, 256, 0, stream>>>(ubuf, vbuf, x, pedge, WbT1, W1a + 256 * HID, agg);
    combine_kernel<<<(int)(NB / 1024), 256, 0, stream>>>(agg, b1b, hbuf, hbuf);   // x1 in place

    // ---- layer 2 ----
    hipMemsetAsync(cnt, 0, N_NODES * sizeof(int), stream);
    hist_kernel<<<histGrid, 256, 0, stream>>>(dst2, cnt);
    scan1_kernel<<<SCAN_B, 256, 0, stream>>>(cnt, cursor, partials);
    scan2_kernel<<<1, 512, 0, stream>>>(partials);
    scan3_kernel<<<SCAN_B, 256, 0, stream>>>(cursor, partials);
    scatter_kernel<<<histGrid, 256, 0, stream>>>(src2, dst2, cursor, pedge);
    mm_mfma_dual_kernel<<<mmGrid, 256, 0, stream>>>(hbuf, WuT2, WvT2, b2a, ubuf, vbuf, N_NODES);
    hipMemsetAsync(agg, 0, NB * sizeof(unsigned), stream);
    edge_kernel<<<edgeGrid, 256, 0, stream>>>(ubuf, vbuf, x, pedge, WbT2, W2a + 256 * HID, agg);
    combine_kernel<<<(int)(NB / 1024), 256, 0, stream>>>(agg, b2b, hbuf, x2buf); // x2

    hipMemsetAsync(pooled, 0, 128 * 512 * sizeof(float), stream);
    pool_kernel<<<N_GRAPHS * 8, 256, 0, stream>>>(hbuf, x2buf, batch, pooled);
    final_kernel<<<N_GRAPHS, 128, 0, stream>>>(pooled, batch, Wf1, bf1, Wf2, bf2, (float*)d_out);
}